// Round 1
// baseline (1750.728 us; speedup 1.0000x reference)
//
#include <hip/hip_runtime.h>
#include <math.h>

// GAT 3-layer, MI355X. Round 0: correct fp32 implementation, CSR-based
// (atomic-free fp aggregation), wave-per-dst-node attention.

#define LRELU(x) ((x) > 0.f ? (x) : 0.2f*(x))

// ---------------- CSR build ----------------
__global__ void k_hist(const int* __restrict__ dst, int* __restrict__ cnt, int E){
  int i = blockIdx.x*blockDim.x + threadIdx.x;
  if (i < E) atomicAdd(&cnt[dst[i]], 1);
}

__global__ void k_scan1(const int* __restrict__ cnt, int* __restrict__ rp,
                        int* __restrict__ bsum, int n){
  __shared__ int sh[256];
  int t = threadIdx.x, i = blockIdx.x*256 + t;
  int v = (i < n) ? cnt[i] : 0;
  sh[t] = v; __syncthreads();
  for (int off = 1; off < 256; off <<= 1){
    int x = (t >= off) ? sh[t-off] : 0;
    __syncthreads();
    sh[t] += x;
    __syncthreads();
  }
  if (i < n) rp[i] = sh[t] - v;          // exclusive within block
  if (t == 255) bsum[blockIdx.x] = sh[t];
}

__global__ void k_scan2(const int* __restrict__ bsum, int* __restrict__ boff, int nb){
  __shared__ int sh[512];
  int t = threadIdx.x;
  int v = (t < nb) ? bsum[t] : 0;
  sh[t] = v; __syncthreads();
  for (int off = 1; off < 512; off <<= 1){
    int x = (t >= off) ? sh[t-off] : 0;
    __syncthreads();
    sh[t] += x;
    __syncthreads();
  }
  if (t < nb) boff[t] = sh[t] - v;
}

__global__ void k_scan3(int* __restrict__ rp, const int* __restrict__ boff,
                        int* __restrict__ fill, int n, int total){
  int i = blockIdx.x*256 + threadIdx.x;
  if (i < n){
    int v = rp[i] + boff[blockIdx.x];
    rp[i] = v; fill[i] = v;
  }
  if (i == 0) rp[n] = total;
}

__global__ void k_scatter(const int* __restrict__ src, const int* __restrict__ dst,
                          int* __restrict__ fill, int* __restrict__ col, int E){
  int i = blockIdx.x*blockDim.x + threadIdx.x;
  if (i < E){
    int pos = atomicAdd(&fill[dst[i]], 1);
    col[pos] = src[i];
  }
}

// ---------------- GEMM (x @ W) fused with al/ar epilogue ----------------
// Tile 16 rows x 128 cols per pass; 256 threads, each owns a 2x4 microtile.
// W (64KB) + padded X tile (8.4KB) in LDS -> 2 blocks/CU.
__global__ __launch_bounds__(256) void k_gemm_att(
    const float* __restrict__ X, const float* __restrict__ W,
    const float* __restrict__ attl, const float* __restrict__ attr,
    float* __restrict__ XW, float* __restrict__ AL, float* __restrict__ AR, int n)
{
  __shared__ float Wl[128*128];
  __shared__ float Xl[16*132];     // pad 132 to break bank aliasing across rows
  int t = threadIdx.x;
  for (int i = t; i < 4096; i += 256) ((float4*)Wl)[i] = ((const float4*)W)[i];
  int cg = t & 31, rg = t >> 5;    // col group 0..31 (4 cols each), row group 0..7 (2 rows)
  float4 alv = ((const float4*)attl)[cg];
  float4 arv = ((const float4*)attr)[cg];
  int ntiles = n >> 4;             // n divisible by 16 (100000 = 16*6250)
  for (int tile = blockIdx.x; tile < ntiles; tile += gridDim.x){
    int row0 = tile << 4;
    __syncthreads();               // protect Xl (and W on first iter)
    for (int i = t; i < 512; i += 256){
      int r = i >> 5, kk = i & 31;
      float4 v = ((const float4*)(X + (size_t)(row0+r)*128))[kk];
      *((float4*)&Xl[r*132 + kk*4]) = v;
    }
    __syncthreads();
    float acc[2][4] = {{0,0,0,0},{0,0,0,0}};
    int r0 = rg*2;
    const float* x0p = &Xl[r0*132];
    const float* x1p = &Xl[(r0+1)*132];
    #pragma unroll 8
    for (int k = 0; k < 128; k++){
      float4 wv = *((const float4*)&Wl[k*128 + cg*4]);
      float x0 = x0p[k], x1 = x1p[k];
      acc[0][0] = fmaf(x0, wv.x, acc[0][0]);
      acc[0][1] = fmaf(x0, wv.y, acc[0][1]);
      acc[0][2] = fmaf(x0, wv.z, acc[0][2]);
      acc[0][3] = fmaf(x0, wv.w, acc[0][3]);
      acc[1][0] = fmaf(x1, wv.x, acc[1][0]);
      acc[1][1] = fmaf(x1, wv.y, acc[1][1]);
      acc[1][2] = fmaf(x1, wv.z, acc[1][2]);
      acc[1][3] = fmaf(x1, wv.w, acc[1][3]);
    }
    int head = cg >> 3;            // cols cg*4..cg*4+3 all in head cg/8
    #pragma unroll
    for (int i = 0; i < 2; i++){
      int row = row0 + r0 + i;
      float4 o; o.x=acc[i][0]; o.y=acc[i][1]; o.z=acc[i][2]; o.w=acc[i][3];
      ((float4*)(XW + (size_t)row*128))[cg] = o;
      float pl = acc[i][0]*alv.x + acc[i][1]*alv.y + acc[i][2]*alv.z + acc[i][3]*alv.w;
      float pr = acc[i][0]*arv.x + acc[i][1]*arv.y + acc[i][2]*arv.z + acc[i][3]*arv.w;
      // reduce over the 8 col-groups of one head (8 consecutive lanes)
      pl += __shfl_xor(pl, 4, 8); pl += __shfl_xor(pl, 2, 8); pl += __shfl_xor(pl, 1, 8);
      pr += __shfl_xor(pr, 4, 8); pr += __shfl_xor(pr, 2, 8); pr += __shfl_xor(pr, 1, 8);
      if ((cg & 7) == 0){ AL[row*4 + head] = pl; AR[row*4 + head] = pr; }
    }
  }
}

// ---------------- Attention + aggregate: one wave per dst node ----------------
// CSR holds only real in-edges; self-loop handled explicitly.
__global__ __launch_bounds__(256) void k_attn(
    const float* __restrict__ XW, const float* __restrict__ AL, const float* __restrict__ AR,
    const int* __restrict__ rp, const int* __restrict__ col,
    const float* __restrict__ bias, float* __restrict__ OUT, int n)
{
  int d = blockIdx.x*4 + (threadIdx.x >> 6);
  int lane = threadIdx.x & 63;
  if (d >= n) return;
  int start = rp[d], end = rp[d+1];
  float4 ald4 = ((const float4*)AL)[d];
  float4 ard4 = ((const float4*)AR)[d];
  float ard[4] = {ard4.x, ard4.y, ard4.z, ard4.w};
  float sl[4];
  sl[0] = LRELU(ald4.x + ard[0]);
  sl[1] = LRELU(ald4.y + ard[1]);
  sl[2] = LRELU(ald4.z + ard[2]);
  sl[3] = LRELU(ald4.w + ard[3]);
  float m[4] = {sl[0], sl[1], sl[2], sl[3]};
  // pass A: segment max (self-loop already in init; max is idempotent per lane)
  for (int base = start; base < end; base += 64){
    int e = base + lane;
    if (e < end){
      int s = col[e];
      float4 a = ((const float4*)AL)[s];
      m[0] = fmaxf(m[0], LRELU(a.x + ard[0]));
      m[1] = fmaxf(m[1], LRELU(a.y + ard[1]));
      m[2] = fmaxf(m[2], LRELU(a.z + ard[2]));
      m[3] = fmaxf(m[3], LRELU(a.w + ard[3]));
    }
  }
  #pragma unroll
  for (int h = 0; h < 4; h++){
    #pragma unroll
    for (int off = 32; off >= 1; off >>= 1)
      m[h] = fmaxf(m[h], __shfl_xor(m[h], off, 64));
  }
  // pass B: segment sum of exp (self term counted once, lane 0)
  float z[4];
  if (lane == 0){
    z[0] = __expf(sl[0]-m[0]); z[1] = __expf(sl[1]-m[1]);
    z[2] = __expf(sl[2]-m[2]); z[3] = __expf(sl[3]-m[3]);
  } else { z[0]=z[1]=z[2]=z[3]=0.f; }
  for (int base = start; base < end; base += 64){
    int e = base + lane;
    if (e < end){
      int s = col[e];
      float4 a = ((const float4*)AL)[s];
      z[0] += __expf(LRELU(a.x + ard[0]) - m[0]);
      z[1] += __expf(LRELU(a.y + ard[1]) - m[1]);
      z[2] += __expf(LRELU(a.z + ard[2]) - m[2]);
      z[3] += __expf(LRELU(a.w + ard[3]) - m[3]);
    }
  }
  #pragma unroll
  for (int h = 0; h < 4; h++){
    #pragma unroll
    for (int off = 32; off >= 1; off >>= 1)
      z[h] += __shfl_xor(z[h], off, 64);
  }
  // pass C: weighted gather-accumulate; lane owns channels 2*lane, 2*lane+1
  int h = lane >> 4;
  float m_h  = (h==0?m[0]:h==1?m[1]:h==2?m[2]:m[3]);
  float z_h  = (h==0?z[0]:h==1?z[1]:h==2?z[2]:z[3]);
  float ar_h = ard[h];
  float sl_h = (h==0?sl[0]:h==1?sl[1]:h==2?sl[2]:sl[3]);
  float rz_h = 1.f / z_h;
  const float2* XW2 = (const float2*)XW;
  float aself = __expf(sl_h - m_h) * rz_h;
  float2 xv = XW2[(size_t)d*64 + lane];
  float acc0 = aself*xv.x, acc1 = aself*xv.y;
  for (int e = start; e < end; e++){
    int s = col[e];
    float alpha = __expf(LRELU(AL[s*4 + h] + ar_h) - m_h) * rz_h;
    float2 xs = XW2[(size_t)s*64 + lane];
    acc0 = fmaf(alpha, xs.x, acc0);
    acc1 = fmaf(alpha, xs.y, acc1);
  }
  int ch = lane*2;
  float o0 = acc0 + bias[ch];
  float o1 = acc1 + bias[ch+1];
  o0 = o0 > 0.f ? o0 : 0.f;   // relu after every GAT layer per reference
  o1 = o1 > 0.f ? o1 : 0.f;
  float2 o; o.x = o0; o.y = o1;
  ((float2*)(OUT + (size_t)d*128))[lane] = o;
}

// ---------------- pooling + MLP head ----------------
__global__ void k_bhist(const int* __restrict__ batch, int* __restrict__ gcnt, int n){
  int i = blockIdx.x*blockDim.x + threadIdx.x;
  if (i < n) atomicAdd(&gcnt[batch[i]], 1);
}

__global__ void k_gscan(const int* __restrict__ gcnt, int* __restrict__ gstart){
  if (threadIdx.x == 0 && blockIdx.x == 0){
    int acc = 0;
    for (int g = 0; g < 64; g++){ gstart[g] = acc; acc += gcnt[g]; }
    gstart[64] = acc;
  }
}

__global__ __launch_bounds__(128) void k_pool(const float* __restrict__ H,
                                              const int* __restrict__ gstart,
                                              float* __restrict__ psum){
  int g = blockIdx.x >> 3, slice = blockIdx.x & 7, t = threadIdx.x;
  int s0 = gstart[g], s1 = gstart[g+1];
  int cntg = s1 - s0;
  int chunk = (cntg + 7) >> 3;
  int lo = s0 + slice*chunk;
  int hi = min(lo + chunk, s1);
  float sum = 0.f;
  for (int i = lo; i < hi; i++) sum += H[(size_t)i*128 + t];
  atomicAdd(&psum[g*128 + t], sum);
}

__global__ __launch_bounds__(128) void k_mlp(const float* __restrict__ psum,
                       const int* __restrict__ gcnt,
                       const float* __restrict__ w1, const float* __restrict__ b1,
                       const float* __restrict__ w2, const float* __restrict__ b2,
                       float* __restrict__ out)
{
  __shared__ float p[128];
  __shared__ float gsh[128];
  __shared__ float lg[10];
  int g = blockIdx.x, t = threadIdx.x;
  float c = fmaxf((float)gcnt[g], 1.f);
  p[t] = psum[g*128 + t] / c;
  __syncthreads();
  float acc = b1[t];
  for (int k = 0; k < 128; k++) acc = fmaf(p[k], w1[k*128 + t], acc);
  gsh[t] = acc > 0.f ? acc : 0.f;
  __syncthreads();
  if (t < 10){
    float a = b2[t];
    for (int k = 0; k < 128; k++) a = fmaf(gsh[k], w2[k*10 + t], a);
    lg[t] = a;
  }
  __syncthreads();
  if (t < 10){
    float mx = lg[0];
    for (int c2 = 1; c2 < 10; c2++) mx = fmaxf(mx, lg[c2]);
    float se = 0.f;
    for (int c2 = 0; c2 < 10; c2++) se += __expf(lg[c2] - mx);
    out[g*10 + t] = lg[t] - mx - logf(se);
  }
}

extern "C" void kernel_launch(void* const* d_in, const int* in_sizes, int n_in,
                              void* d_out, int out_size, void* d_ws, size_t ws_size,
                              hipStream_t stream)
{
  const float* x    = (const float*)d_in[0];
  const int* eidx   = (const int*)d_in[1];
  const int* batch  = (const int*)d_in[2];
  const float* W[3]  = {(const float*)d_in[3], (const float*)d_in[7],  (const float*)d_in[11]};
  const float* al[3] = {(const float*)d_in[4], (const float*)d_in[8],  (const float*)d_in[12]};
  const float* ar[3] = {(const float*)d_in[5], (const float*)d_in[9],  (const float*)d_in[13]};
  const float* bs[3] = {(const float*)d_in[6], (const float*)d_in[10], (const float*)d_in[14]};
  const float* l1w = (const float*)d_in[15];
  const float* l1b = (const float*)d_in[16];
  const float* l2w = (const float*)d_in[17];
  const float* l2b = (const float*)d_in[18];
  int E = in_sizes[1] / 2;
  int n = in_sizes[2];            // N_NODES = 100000 (divisible by 16)
  const int* srcp = eidx;
  const int* dstp = eidx + E;

  char* wsp = (char*)d_ws;
  auto alloc = [&](size_t bytes){ void* p = (void*)wsp; wsp += (bytes + 255) & ~(size_t)255; return p; };
  float* xw   = (float*)alloc((size_t)n*128*4);   // 51.2 MB
  float* hbuf = (float*)alloc((size_t)n*128*4);   // 51.2 MB
  float* ALb  = (float*)alloc((size_t)n*4*4);
  float* ARb  = (float*)alloc((size_t)n*4*4);
  int* rp     = (int*)alloc((size_t)(n+1)*4);
  int* fill   = (int*)alloc((size_t)n*4);
  int* cnt    = (int*)alloc((size_t)n*4);
  int* colA   = (int*)alloc((size_t)E*4);         // 6.4 MB
  int* bsum   = (int*)alloc(512*4);
  int* boff   = (int*)alloc(512*4);
  float* psum = (float*)alloc(64*128*4);
  int* gcnt   = (int*)alloc(256);
  int* gstart = (int*)alloc(65*4);

  float* outlog = (float*)d_out;
  float* h3     = (float*)d_out + 64*10;

  hipMemsetAsync(cnt,  0, (size_t)n*4, stream);
  hipMemsetAsync(psum, 0, 64*128*4,    stream);
  hipMemsetAsync(gcnt, 0, 64*4,        stream);

  int nb = (n + 255)/256;   // 391 <= 512
  k_hist   <<<(E+255)/256, 256, 0, stream>>>(dstp, cnt, E);
  k_scan1  <<<nb, 256, 0, stream>>>(cnt, rp, bsum, n);
  k_scan2  <<<1, 512, 0, stream>>>(bsum, boff, nb);
  k_scan3  <<<nb, 256, 0, stream>>>(rp, boff, fill, n, E);
  k_scatter<<<(E+255)/256, 256, 0, stream>>>(srcp, dstp, fill, colA, E);

  k_bhist<<<nb, 256, 0, stream>>>(batch, gcnt, n);
  k_gscan<<<1, 64, 0, stream>>>(gcnt, gstart);

  const int GG = 512;  // 2 blocks/CU resident
  // layer 1
  k_gemm_att<<<GG, 256, 0, stream>>>(x, W[0], al[0], ar[0], xw, ALb, ARb, n);
  k_attn<<<(n+3)/4, 256, 0, stream>>>(xw, ALb, ARb, rp, colA, bs[0], hbuf, n);
  // layer 2
  k_gemm_att<<<GG, 256, 0, stream>>>(hbuf, W[1], al[1], ar[1], xw, ALb, ARb, n);
  k_attn<<<(n+3)/4, 256, 0, stream>>>(xw, ALb, ARb, rp, colA, bs[1], hbuf, n);
  // layer 3 -> write h3 straight into d_out
  k_gemm_att<<<GG, 256, 0, stream>>>(hbuf, W[2], al[2], ar[2], xw, ALb, ARb, n);
  k_attn<<<(n+3)/4, 256, 0, stream>>>(xw, ALb, ARb, rp, colA, bs[2], h3, n);

  k_pool<<<64*8, 128, 0, stream>>>(h3, gstart, psum);
  k_mlp <<<64, 128, 0, stream>>>(psum, gcnt, l1w, l1b, l2w, l2b, outlog);
}

// Round 2
// 1229.579 us; speedup vs baseline: 1.4238x; 1.4238x over previous
//
#include <hip/hip_runtime.h>
#include <math.h>

// GAT 3-layer, MI355X. Round 1: remove the contended-atomic batch histogram
// (sorted batch -> binary-search graph boundaries). Rest unchanged from R0.

#define LRELU(x) ((x) > 0.f ? (x) : 0.2f*(x))

// ---------------- CSR build ----------------
__global__ void k_hist(const int* __restrict__ dst, int* __restrict__ cnt, int E){
  int i = blockIdx.x*blockDim.x + threadIdx.x;
  if (i < E) atomicAdd(&cnt[dst[i]], 1);
}

__global__ void k_scan1(const int* __restrict__ cnt, int* __restrict__ rp,
                        int* __restrict__ bsum, int n){
  __shared__ int sh[256];
  int t = threadIdx.x, i = blockIdx.x*256 + t;
  int v = (i < n) ? cnt[i] : 0;
  sh[t] = v; __syncthreads();
  for (int off = 1; off < 256; off <<= 1){
    int x = (t >= off) ? sh[t-off] : 0;
    __syncthreads();
    sh[t] += x;
    __syncthreads();
  }
  if (i < n) rp[i] = sh[t] - v;          // exclusive within block
  if (t == 255) bsum[blockIdx.x] = sh[t];
}

__global__ void k_scan2(const int* __restrict__ bsum, int* __restrict__ boff, int nb){
  __shared__ int sh[512];
  int t = threadIdx.x;
  int v = (t < nb) ? bsum[t] : 0;
  sh[t] = v; __syncthreads();
  for (int off = 1; off < 512; off <<= 1){
    int x = (t >= off) ? sh[t-off] : 0;
    __syncthreads();
    sh[t] += x;
    __syncthreads();
  }
  if (t < nb) boff[t] = sh[t] - v;
}

__global__ void k_scan3(int* __restrict__ rp, const int* __restrict__ boff,
                        int* __restrict__ fill, int n, int total){
  int i = blockIdx.x*256 + threadIdx.x;
  if (i < n){
    int v = rp[i] + boff[blockIdx.x];
    rp[i] = v; fill[i] = v;
  }
  if (i == 0) rp[n] = total;
}

__global__ void k_scatter(const int* __restrict__ src, const int* __restrict__ dst,
                          int* __restrict__ fill, int* __restrict__ col, int E){
  int i = blockIdx.x*blockDim.x + threadIdx.x;
  if (i < E){
    int pos = atomicAdd(&fill[dst[i]], 1);
    col[pos] = src[i];
  }
}

// ---------------- graph boundaries via binary search (batch is sorted) ----
__global__ void k_bounds(const int* __restrict__ batch, int* __restrict__ gstart, int n){
  int g = threadIdx.x;
  if (g > 64) return;
  int lo = 0, hi = n;
  while (lo < hi){
    int mid = (lo + hi) >> 1;
    if (batch[mid] < g) lo = mid + 1; else hi = mid;
  }
  gstart[g] = lo;   // first index with batch[i] >= g; gstart[64] = n
}

// ---------------- GEMM (x @ W) fused with al/ar epilogue ----------------
// Tile 16 rows x 128 cols per pass; 256 threads, each owns a 2x4 microtile.
// W (64KB) + padded X tile (8.4KB) in LDS -> 2 blocks/CU.
__global__ __launch_bounds__(256) void k_gemm_att(
    const float* __restrict__ X, const float* __restrict__ W,
    const float* __restrict__ attl, const float* __restrict__ attr,
    float* __restrict__ XW, float* __restrict__ AL, float* __restrict__ AR, int n)
{
  __shared__ float Wl[128*128];
  __shared__ float Xl[16*132];     // pad 132 to break bank aliasing across rows
  int t = threadIdx.x;
  for (int i = t; i < 4096; i += 256) ((float4*)Wl)[i] = ((const float4*)W)[i];
  int cg = t & 31, rg = t >> 5;    // col group 0..31 (4 cols each), row group 0..7 (2 rows)
  float4 alv = ((const float4*)attl)[cg];
  float4 arv = ((const float4*)attr)[cg];
  int ntiles = n >> 4;             // n divisible by 16 (100000 = 16*6250)
  for (int tile = blockIdx.x; tile < ntiles; tile += gridDim.x){
    int row0 = tile << 4;
    __syncthreads();               // protect Xl (and W on first iter)
    for (int i = t; i < 512; i += 256){
      int r = i >> 5, kk = i & 31;
      float4 v = ((const float4*)(X + (size_t)(row0+r)*128))[kk];
      *((float4*)&Xl[r*132 + kk*4]) = v;
    }
    __syncthreads();
    float acc[2][4] = {{0,0,0,0},{0,0,0,0}};
    int r0 = rg*2;
    const float* x0p = &Xl[r0*132];
    const float* x1p = &Xl[(r0+1)*132];
    #pragma unroll 8
    for (int k = 0; k < 128; k++){
      float4 wv = *((const float4*)&Wl[k*128 + cg*4]);
      float x0 = x0p[k], x1 = x1p[k];
      acc[0][0] = fmaf(x0, wv.x, acc[0][0]);
      acc[0][1] = fmaf(x0, wv.y, acc[0][1]);
      acc[0][2] = fmaf(x0, wv.z, acc[0][2]);
      acc[0][3] = fmaf(x0, wv.w, acc[0][3]);
      acc[1][0] = fmaf(x1, wv.x, acc[1][0]);
      acc[1][1] = fmaf(x1, wv.y, acc[1][1]);
      acc[1][2] = fmaf(x1, wv.z, acc[1][2]);
      acc[1][3] = fmaf(x1, wv.w, acc[1][3]);
    }
    int head = cg >> 3;            // cols cg*4..cg*4+3 all in head cg/8
    #pragma unroll
    for (int i = 0; i < 2; i++){
      int row = row0 + r0 + i;
      float4 o; o.x=acc[i][0]; o.y=acc[i][1]; o.z=acc[i][2]; o.w=acc[i][3];
      ((float4*)(XW + (size_t)row*128))[cg] = o;
      float pl = acc[i][0]*alv.x + acc[i][1]*alv.y + acc[i][2]*alv.z + acc[i][3]*alv.w;
      float pr = acc[i][0]*arv.x + acc[i][1]*arv.y + acc[i][2]*arv.z + acc[i][3]*arv.w;
      // reduce over the 8 col-groups of one head (8 consecutive lanes)
      pl += __shfl_xor(pl, 4, 8); pl += __shfl_xor(pl, 2, 8); pl += __shfl_xor(pl, 1, 8);
      pr += __shfl_xor(pr, 4, 8); pr += __shfl_xor(pr, 2, 8); pr += __shfl_xor(pr, 1, 8);
      if ((cg & 7) == 0){ AL[row*4 + head] = pl; AR[row*4 + head] = pr; }
    }
  }
}

// ---------------- Attention + aggregate: one wave per dst node ----------------
// CSR holds only real in-edges; self-loop handled explicitly.
__global__ __launch_bounds__(256) void k_attn(
    const float* __restrict__ XW, const float* __restrict__ AL, const float* __restrict__ AR,
    const int* __restrict__ rp, const int* __restrict__ col,
    const float* __restrict__ bias, float* __restrict__ OUT, int n)
{
  int d = blockIdx.x*4 + (threadIdx.x >> 6);
  int lane = threadIdx.x & 63;
  if (d >= n) return;
  int start = rp[d], end = rp[d+1];
  float4 ald4 = ((const float4*)AL)[d];
  float4 ard4 = ((const float4*)AR)[d];
  float ard[4] = {ard4.x, ard4.y, ard4.z, ard4.w};
  float sl[4];
  sl[0] = LRELU(ald4.x + ard[0]);
  sl[1] = LRELU(ald4.y + ard[1]);
  sl[2] = LRELU(ald4.z + ard[2]);
  sl[3] = LRELU(ald4.w + ard[3]);
  float m[4] = {sl[0], sl[1], sl[2], sl[3]};
  // pass A: segment max (self-loop already in init; max is idempotent per lane)
  for (int base = start; base < end; base += 64){
    int e = base + lane;
    if (e < end){
      int s = col[e];
      float4 a = ((const float4*)AL)[s];
      m[0] = fmaxf(m[0], LRELU(a.x + ard[0]));
      m[1] = fmaxf(m[1], LRELU(a.y + ard[1]));
      m[2] = fmaxf(m[2], LRELU(a.z + ard[2]));
      m[3] = fmaxf(m[3], LRELU(a.w + ard[3]));
    }
  }
  #pragma unroll
  for (int h = 0; h < 4; h++){
    #pragma unroll
    for (int off = 32; off >= 1; off >>= 1)
      m[h] = fmaxf(m[h], __shfl_xor(m[h], off, 64));
  }
  // pass B: segment sum of exp (self term counted once, lane 0)
  float z[4];
  if (lane == 0){
    z[0] = __expf(sl[0]-m[0]); z[1] = __expf(sl[1]-m[1]);
    z[2] = __expf(sl[2]-m[2]); z[3] = __expf(sl[3]-m[3]);
  } else { z[0]=z[1]=z[2]=z[3]=0.f; }
  for (int base = start; base < end; base += 64){
    int e = base + lane;
    if (e < end){
      int s = col[e];
      float4 a = ((const float4*)AL)[s];
      z[0] += __expf(LRELU(a.x + ard[0]) - m[0]);
      z[1] += __expf(LRELU(a.y + ard[1]) - m[1]);
      z[2] += __expf(LRELU(a.z + ard[2]) - m[2]);
      z[3] += __expf(LRELU(a.w + ard[3]) - m[3]);
    }
  }
  #pragma unroll
  for (int h = 0; h < 4; h++){
    #pragma unroll
    for (int off = 32; off >= 1; off >>= 1)
      z[h] += __shfl_xor(z[h], off, 64);
  }
  // pass C: weighted gather-accumulate; lane owns channels 2*lane, 2*lane+1
  int h = lane >> 4;
  float m_h  = (h==0?m[0]:h==1?m[1]:h==2?m[2]:m[3]);
  float z_h  = (h==0?z[0]:h==1?z[1]:h==2?z[2]:z[3]);
  float ar_h = ard[h];
  float sl_h = (h==0?sl[0]:h==1?sl[1]:h==2?sl[2]:sl[3]);
  float rz_h = 1.f / z_h;
  const float2* XW2 = (const float2*)XW;
  float aself = __expf(sl_h - m_h) * rz_h;
  float2 xv = XW2[(size_t)d*64 + lane];
  float acc0 = aself*xv.x, acc1 = aself*xv.y;
  for (int e = start; e < end; e++){
    int s = col[e];
    float alpha = __expf(LRELU(AL[s*4 + h] + ar_h) - m_h) * rz_h;
    float2 xs = XW2[(size_t)s*64 + lane];
    acc0 = fmaf(alpha, xs.x, acc0);
    acc1 = fmaf(alpha, xs.y, acc1);
  }
  int ch = lane*2;
  float o0 = acc0 + bias[ch];
  float o1 = acc1 + bias[ch+1];
  o0 = o0 > 0.f ? o0 : 0.f;   // relu after every GAT layer per reference
  o1 = o1 > 0.f ? o1 : 0.f;
  float2 o; o.x = o0; o.y = o1;
  ((float2*)(OUT + (size_t)d*128))[lane] = o;
}

// ---------------- pooling + MLP head ----------------
__global__ __launch_bounds__(128) void k_pool(const float* __restrict__ H,
                                              const int* __restrict__ gstart,
                                              float* __restrict__ psum){
  int g = blockIdx.x >> 3, slice = blockIdx.x & 7, t = threadIdx.x;
  int s0 = gstart[g], s1 = gstart[g+1];
  int cntg = s1 - s0;
  int chunk = (cntg + 7) >> 3;
  int lo = s0 + slice*chunk;
  int hi = min(lo + chunk, s1);
  float sum = 0.f;
  for (int i = lo; i < hi; i++) sum += H[(size_t)i*128 + t];
  atomicAdd(&psum[g*128 + t], sum);
}

__global__ __launch_bounds__(128) void k_mlp(const float* __restrict__ psum,
                       const int* __restrict__ gstart,
                       const float* __restrict__ w1, const float* __restrict__ b1,
                       const float* __restrict__ w2, const float* __restrict__ b2,
                       float* __restrict__ out)
{
  __shared__ float p[128];
  __shared__ float gsh[128];
  __shared__ float lg[10];
  int g = blockIdx.x, t = threadIdx.x;
  float c = fmaxf((float)(gstart[g+1] - gstart[g]), 1.f);
  p[t] = psum[g*128 + t] / c;
  __syncthreads();
  float acc = b1[t];
  for (int k = 0; k < 128; k++) acc = fmaf(p[k], w1[k*128 + t], acc);
  gsh[t] = acc > 0.f ? acc : 0.f;
  __syncthreads();
  if (t < 10){
    float a = b2[t];
    for (int k = 0; k < 128; k++) a = fmaf(gsh[k], w2[k*10 + t], a);
    lg[t] = a;
  }
  __syncthreads();
  if (t < 10){
    float mx = lg[0];
    for (int c2 = 1; c2 < 10; c2++) mx = fmaxf(mx, lg[c2]);
    float se = 0.f;
    for (int c2 = 0; c2 < 10; c2++) se += __expf(lg[c2] - mx);
    out[g*10 + t] = lg[t] - mx - logf(se);
  }
}

extern "C" void kernel_launch(void* const* d_in, const int* in_sizes, int n_in,
                              void* d_out, int out_size, void* d_ws, size_t ws_size,
                              hipStream_t stream)
{
  const float* x    = (const float*)d_in[0];
  const int* eidx   = (const int*)d_in[1];
  const int* batch  = (const int*)d_in[2];
  const float* W[3]  = {(const float*)d_in[3], (const float*)d_in[7],  (const float*)d_in[11]};
  const float* al[3] = {(const float*)d_in[4], (const float*)d_in[8],  (const float*)d_in[12]};
  const float* ar[3] = {(const float*)d_in[5], (const float*)d_in[9],  (const float*)d_in[13]};
  const float* bs[3] = {(const float*)d_in[6], (const float*)d_in[10], (const float*)d_in[14]};
  const float* l1w = (const float*)d_in[15];
  const float* l1b = (const float*)d_in[16];
  const float* l2w = (const float*)d_in[17];
  const float* l2b = (const float*)d_in[18];
  int E = in_sizes[1] / 2;
  int n = in_sizes[2];            // N_NODES = 100000 (divisible by 16)
  const int* srcp = eidx;
  const int* dstp = eidx + E;

  char* wsp = (char*)d_ws;
  auto alloc = [&](size_t bytes){ void* p = (void*)wsp; wsp += (bytes + 255) & ~(size_t)255; return p; };
  float* xw   = (float*)alloc((size_t)n*128*4);   // 51.2 MB
  float* hbuf = (float*)alloc((size_t)n*128*4);   // 51.2 MB
  float* ALb  = (float*)alloc((size_t)n*4*4);
  float* ARb  = (float*)alloc((size_t)n*4*4);
  int* rp     = (int*)alloc((size_t)(n+1)*4);
  int* fill   = (int*)alloc((size_t)n*4);
  int* cnt    = (int*)alloc((size_t)n*4);
  int* colA   = (int*)alloc((size_t)E*4);         // 6.4 MB
  int* bsum   = (int*)alloc(512*4);
  int* boff   = (int*)alloc(512*4);
  float* psum = (float*)alloc(64*128*4);
  int* gstart = (int*)alloc(65*4);

  float* outlog = (float*)d_out;
  float* h3     = (float*)d_out + 64*10;

  hipMemsetAsync(cnt,  0, (size_t)n*4, stream);
  hipMemsetAsync(psum, 0, 64*128*4,    stream);

  int nb = (n + 255)/256;   // 391 <= 512
  k_hist   <<<(E+255)/256, 256, 0, stream>>>(dstp, cnt, E);
  k_scan1  <<<nb, 256, 0, stream>>>(cnt, rp, bsum, n);
  k_scan2  <<<1, 512, 0, stream>>>(bsum, boff, nb);
  k_scan3  <<<nb, 256, 0, stream>>>(rp, boff, fill, n, E);
  k_scatter<<<(E+255)/256, 256, 0, stream>>>(srcp, dstp, fill, colA, E);

  k_bounds<<<1, 128, 0, stream>>>(batch, gstart, n);

  const int GG = 512;  // 2 blocks/CU resident
  // layer 1
  k_gemm_att<<<GG, 256, 0, stream>>>(x, W[0], al[0], ar[0], xw, ALb, ARb, n);
  k_attn<<<(n+3)/4, 256, 0, stream>>>(xw, ALb, ARb, rp, colA, bs[0], hbuf, n);
  // layer 2
  k_gemm_att<<<GG, 256, 0, stream>>>(hbuf, W[1], al[1], ar[1], xw, ALb, ARb, n);
  k_attn<<<(n+3)/4, 256, 0, stream>>>(xw, ALb, ARb, rp, colA, bs[1], hbuf, n);
  // layer 3 -> write h3 straight into d_out
  k_gemm_att<<<GG, 256, 0, stream>>>(hbuf, W[2], al[2], ar[2], xw, ALb, ARb, n);
  k_attn<<<(n+3)/4, 256, 0, stream>>>(xw, ALb, ARb, rp, colA, bs[2], h3, n);

  k_pool<<<64*8, 128, 0, stream>>>(h3, gstart, psum);
  k_mlp <<<64, 128, 0, stream>>>(psum, gstart, l1w, l1b, l2w, l2b, outlog);
}

// Round 3
// 1169.850 us; speedup vs baseline: 1.4965x; 1.0511x over previous
//
#include <hip/hip_runtime.h>
#include <math.h>

// GAT 3-layer, MI355X. Round 2: xw stored as bf16 -> halves the dominant
// pass-C edge gather (820 MB -> 410 MB logical per layer). al/ar logits
// still computed from fp32 accumulators in the GEMM epilogue.

#define LRELU(x) ((x) > 0.f ? (x) : 0.2f*(x))

__device__ inline unsigned short f2bf(float f){
  unsigned u = __float_as_uint(f);
  u += 0x7fff + ((u >> 16) & 1);   // round-to-nearest-even
  return (unsigned short)(u >> 16);
}

// ---------------- CSR build ----------------
__global__ void k_hist(const int* __restrict__ dst, int* __restrict__ cnt, int E){
  int i = blockIdx.x*blockDim.x + threadIdx.x;
  if (i < E) atomicAdd(&cnt[dst[i]], 1);
}

__global__ void k_scan1(const int* __restrict__ cnt, int* __restrict__ rp,
                        int* __restrict__ bsum, int n){
  __shared__ int sh[256];
  int t = threadIdx.x, i = blockIdx.x*256 + t;
  int v = (i < n) ? cnt[i] : 0;
  sh[t] = v; __syncthreads();
  for (int off = 1; off < 256; off <<= 1){
    int x = (t >= off) ? sh[t-off] : 0;
    __syncthreads();
    sh[t] += x;
    __syncthreads();
  }
  if (i < n) rp[i] = sh[t] - v;          // exclusive within block
  if (t == 255) bsum[blockIdx.x] = sh[t];
}

__global__ void k_scan2(const int* __restrict__ bsum, int* __restrict__ boff, int nb){
  __shared__ int sh[512];
  int t = threadIdx.x;
  int v = (t < nb) ? bsum[t] : 0;
  sh[t] = v; __syncthreads();
  for (int off = 1; off < 512; off <<= 1){
    int x = (t >= off) ? sh[t-off] : 0;
    __syncthreads();
    sh[t] += x;
    __syncthreads();
  }
  if (t < nb) boff[t] = sh[t] - v;
}

__global__ void k_scan3(int* __restrict__ rp, const int* __restrict__ boff,
                        int* __restrict__ fill, int n, int total){
  int i = blockIdx.x*256 + threadIdx.x;
  if (i < n){
    int v = rp[i] + boff[blockIdx.x];
    rp[i] = v; fill[i] = v;
  }
  if (i == 0) rp[n] = total;
}

__global__ void k_scatter(const int* __restrict__ src, const int* __restrict__ dst,
                          int* __restrict__ fill, int* __restrict__ col, int E){
  int i = blockIdx.x*blockDim.x + threadIdx.x;
  if (i < E){
    int pos = atomicAdd(&fill[dst[i]], 1);
    col[pos] = src[i];
  }
}

// ---------------- graph boundaries via binary search (batch is sorted) ----
__global__ void k_bounds(const int* __restrict__ batch, int* __restrict__ gstart, int n){
  int g = threadIdx.x;
  if (g > 64) return;
  int lo = 0, hi = n;
  while (lo < hi){
    int mid = (lo + hi) >> 1;
    if (batch[mid] < g) lo = mid + 1; else hi = mid;
  }
  gstart[g] = lo;   // first index with batch[i] >= g; gstart[64] = n
}

// ---------------- GEMM (x @ W) fused with al/ar epilogue ----------------
// Tile 16 rows x 128 cols; 256 threads, 2x4 microtile each. XW stored bf16.
__global__ __launch_bounds__(256) void k_gemm_att(
    const float* __restrict__ X, const float* __restrict__ W,
    const float* __restrict__ attl, const float* __restrict__ attr,
    unsigned short* __restrict__ XW, float* __restrict__ AL, float* __restrict__ AR, int n)
{
  __shared__ float Wl[128*128];
  __shared__ float Xl[16*132];     // pad 132 to break bank aliasing across rows
  int t = threadIdx.x;
  for (int i = t; i < 4096; i += 256) ((float4*)Wl)[i] = ((const float4*)W)[i];
  int cg = t & 31, rg = t >> 5;    // col group 0..31 (4 cols each), row group 0..7 (2 rows)
  float4 alv = ((const float4*)attl)[cg];
  float4 arv = ((const float4*)attr)[cg];
  int ntiles = n >> 4;             // n divisible by 16 (100000 = 16*6250)
  for (int tile = blockIdx.x; tile < ntiles; tile += gridDim.x){
    int row0 = tile << 4;
    __syncthreads();               // protect Xl (and W on first iter)
    for (int i = t; i < 512; i += 256){
      int r = i >> 5, kk = i & 31;
      float4 v = ((const float4*)(X + (size_t)(row0+r)*128))[kk];
      *((float4*)&Xl[r*132 + kk*4]) = v;
    }
    __syncthreads();
    float acc[2][4] = {{0,0,0,0},{0,0,0,0}};
    int r0 = rg*2;
    const float* x0p = &Xl[r0*132];
    const float* x1p = &Xl[(r0+1)*132];
    #pragma unroll 8
    for (int k = 0; k < 128; k++){
      float4 wv = *((const float4*)&Wl[k*128 + cg*4]);
      float x0 = x0p[k], x1 = x1p[k];
      acc[0][0] = fmaf(x0, wv.x, acc[0][0]);
      acc[0][1] = fmaf(x0, wv.y, acc[0][1]);
      acc[0][2] = fmaf(x0, wv.z, acc[0][2]);
      acc[0][3] = fmaf(x0, wv.w, acc[0][3]);
      acc[1][0] = fmaf(x1, wv.x, acc[1][0]);
      acc[1][1] = fmaf(x1, wv.y, acc[1][1]);
      acc[1][2] = fmaf(x1, wv.z, acc[1][2]);
      acc[1][3] = fmaf(x1, wv.w, acc[1][3]);
    }
    int head = cg >> 3;            // cols cg*4..cg*4+3 all in head cg/8
    #pragma unroll
    for (int i = 0; i < 2; i++){
      int row = row0 + r0 + i;
      ushort4 o;
      o.x = f2bf(acc[i][0]); o.y = f2bf(acc[i][1]);
      o.z = f2bf(acc[i][2]); o.w = f2bf(acc[i][3]);
      ((ushort4*)(XW + (size_t)row*128))[cg] = o;
      float pl = acc[i][0]*alv.x + acc[i][1]*alv.y + acc[i][2]*alv.z + acc[i][3]*alv.w;
      float pr = acc[i][0]*arv.x + acc[i][1]*arv.y + acc[i][2]*arv.z + acc[i][3]*arv.w;
      // reduce over the 8 col-groups of one head (8 consecutive lanes)
      pl += __shfl_xor(pl, 4, 8); pl += __shfl_xor(pl, 2, 8); pl += __shfl_xor(pl, 1, 8);
      pr += __shfl_xor(pr, 4, 8); pr += __shfl_xor(pr, 2, 8); pr += __shfl_xor(pr, 1, 8);
      if ((cg & 7) == 0){ AL[row*4 + head] = pl; AR[row*4 + head] = pr; }
    }
  }
}

// ---------------- Attention + aggregate: one wave per dst node ----------------
// CSR holds only real in-edges; self-loop handled explicitly. XW is bf16.
__global__ __launch_bounds__(256) void k_attn(
    const unsigned short* __restrict__ XW, const float* __restrict__ AL, const float* __restrict__ AR,
    const int* __restrict__ rp, const int* __restrict__ col,
    const float* __restrict__ bias, float* __restrict__ OUT, int n)
{
  int d = blockIdx.x*4 + (threadIdx.x >> 6);
  int lane = threadIdx.x & 63;
  if (d >= n) return;
  int start = rp[d], end = rp[d+1];
  float4 ald4 = ((const float4*)AL)[d];
  float4 ard4 = ((const float4*)AR)[d];
  float ard[4] = {ard4.x, ard4.y, ard4.z, ard4.w};
  float sl[4];
  sl[0] = LRELU(ald4.x + ard[0]);
  sl[1] = LRELU(ald4.y + ard[1]);
  sl[2] = LRELU(ald4.z + ard[2]);
  sl[3] = LRELU(ald4.w + ard[3]);
  float m[4] = {sl[0], sl[1], sl[2], sl[3]};
  // pass A: segment max
  for (int base = start; base < end; base += 64){
    int e = base + lane;
    if (e < end){
      int s = col[e];
      float4 a = ((const float4*)AL)[s];
      m[0] = fmaxf(m[0], LRELU(a.x + ard[0]));
      m[1] = fmaxf(m[1], LRELU(a.y + ard[1]));
      m[2] = fmaxf(m[2], LRELU(a.z + ard[2]));
      m[3] = fmaxf(m[3], LRELU(a.w + ard[3]));
    }
  }
  #pragma unroll
  for (int h = 0; h < 4; h++){
    #pragma unroll
    for (int off = 32; off >= 1; off >>= 1)
      m[h] = fmaxf(m[h], __shfl_xor(m[h], off, 64));
  }
  // pass B: segment sum of exp (self term counted once, lane 0)
  float z[4];
  if (lane == 0){
    z[0] = __expf(sl[0]-m[0]); z[1] = __expf(sl[1]-m[1]);
    z[2] = __expf(sl[2]-m[2]); z[3] = __expf(sl[3]-m[3]);
  } else { z[0]=z[1]=z[2]=z[3]=0.f; }
  for (int base = start; base < end; base += 64){
    int e = base + lane;
    if (e < end){
      int s = col[e];
      float4 a = ((const float4*)AL)[s];
      z[0] += __expf(LRELU(a.x + ard[0]) - m[0]);
      z[1] += __expf(LRELU(a.y + ard[1]) - m[1]);
      z[2] += __expf(LRELU(a.z + ard[2]) - m[2]);
      z[3] += __expf(LRELU(a.w + ard[3]) - m[3]);
    }
  }
  #pragma unroll
  for (int h = 0; h < 4; h++){
    #pragma unroll
    for (int off = 32; off >= 1; off >>= 1)
      z[h] += __shfl_xor(z[h], off, 64);
  }
  // pass C: weighted gather-accumulate; lane owns channels 2*lane, 2*lane+1
  int h = lane >> 4;
  float m_h  = (h==0?m[0]:h==1?m[1]:h==2?m[2]:m[3]);
  float z_h  = (h==0?z[0]:h==1?z[1]:h==2?z[2]:z[3]);
  float ar_h = ard[h];
  float sl_h = (h==0?sl[0]:h==1?sl[1]:h==2?sl[2]:sl[3]);
  float rz_h = 1.f / z_h;
  const unsigned* XWr = (const unsigned*)XW;   // one uint = 2 bf16 channels
  float aself = __expf(sl_h - m_h) * rz_h;
  unsigned v = XWr[(size_t)d*64 + lane];
  float xv0 = __uint_as_float(v << 16);
  float xv1 = __uint_as_float(v & 0xffff0000u);
  float acc0 = aself*xv0, acc1 = aself*xv1;
  for (int e = start; e < end; e++){
    int s = col[e];
    float alpha = __expf(LRELU(AL[s*4 + h] + ar_h) - m_h) * rz_h;
    unsigned u = XWr[(size_t)s*64 + lane];
    float xs0 = __uint_as_float(u << 16);
    float xs1 = __uint_as_float(u & 0xffff0000u);
    acc0 = fmaf(alpha, xs0, acc0);
    acc1 = fmaf(alpha, xs1, acc1);
  }
  int ch = lane*2;
  float o0 = acc0 + bias[ch];
  float o1 = acc1 + bias[ch+1];
  o0 = o0 > 0.f ? o0 : 0.f;   // relu after every GAT layer per reference
  o1 = o1 > 0.f ? o1 : 0.f;
  float2 o; o.x = o0; o.y = o1;
  ((float2*)(OUT + (size_t)d*128))[lane] = o;
}

// ---------------- pooling + MLP head ----------------
__global__ __launch_bounds__(128) void k_pool(const float* __restrict__ H,
                                              const int* __restrict__ gstart,
                                              float* __restrict__ psum){
  int g = blockIdx.x >> 3, slice = blockIdx.x & 7, t = threadIdx.x;
  int s0 = gstart[g], s1 = gstart[g+1];
  int cntg = s1 - s0;
  int chunk = (cntg + 7) >> 3;
  int lo = s0 + slice*chunk;
  int hi = min(lo + chunk, s1);
  float sum = 0.f;
  for (int i = lo; i < hi; i++) sum += H[(size_t)i*128 + t];
  atomicAdd(&psum[g*128 + t], sum);
}

__global__ __launch_bounds__(128) void k_mlp(const float* __restrict__ psum,
                       const int* __restrict__ gstart,
                       const float* __restrict__ w1, const float* __restrict__ b1,
                       const float* __restrict__ w2, const float* __restrict__ b2,
                       float* __restrict__ out)
{
  __shared__ float p[128];
  __shared__ float gsh[128];
  __shared__ float lg[10];
  int g = blockIdx.x, t = threadIdx.x;
  float c = fmaxf((float)(gstart[g+1] - gstart[g]), 1.f);
  p[t] = psum[g*128 + t] / c;
  __syncthreads();
  float acc = b1[t];
  for (int k = 0; k < 128; k++) acc = fmaf(p[k], w1[k*128 + t], acc);
  gsh[t] = acc > 0.f ? acc : 0.f;
  __syncthreads();
  if (t < 10){
    float a = b2[t];
    for (int k = 0; k < 128; k++) a = fmaf(gsh[k], w2[k*10 + t], a);
    lg[t] = a;
  }
  __syncthreads();
  if (t < 10){
    float mx = lg[0];
    for (int c2 = 1; c2 < 10; c2++) mx = fmaxf(mx, lg[c2]);
    float se = 0.f;
    for (int c2 = 0; c2 < 10; c2++) se += __expf(lg[c2] - mx);
    out[g*10 + t] = lg[t] - mx - logf(se);
  }
}

extern "C" void kernel_launch(void* const* d_in, const int* in_sizes, int n_in,
                              void* d_out, int out_size, void* d_ws, size_t ws_size,
                              hipStream_t stream)
{
  const float* x    = (const float*)d_in[0];
  const int* eidx   = (const int*)d_in[1];
  const int* batch  = (const int*)d_in[2];
  const float* W[3]  = {(const float*)d_in[3], (const float*)d_in[7],  (const float*)d_in[11]};
  const float* al[3] = {(const float*)d_in[4], (const float*)d_in[8],  (const float*)d_in[12]};
  const float* ar[3] = {(const float*)d_in[5], (const float*)d_in[9],  (const float*)d_in[13]};
  const float* bs[3] = {(const float*)d_in[6], (const float*)d_in[10], (const float*)d_in[14]};
  const float* l1w = (const float*)d_in[15];
  const float* l1b = (const float*)d_in[16];
  const float* l2w = (const float*)d_in[17];
  const float* l2b = (const float*)d_in[18];
  int E = in_sizes[1] / 2;
  int n = in_sizes[2];            // N_NODES = 100000 (divisible by 16)
  const int* srcp = eidx;
  const int* dstp = eidx + E;

  char* wsp = (char*)d_ws;
  auto alloc = [&](size_t bytes){ void* p = (void*)wsp; wsp += (bytes + 255) & ~(size_t)255; return p; };
  unsigned short* xw = (unsigned short*)alloc((size_t)n*128*2);  // 25.6 MB bf16
  float* hbuf = (float*)alloc((size_t)n*128*4);   // 51.2 MB
  float* ALb  = (float*)alloc((size_t)n*4*4);
  float* ARb  = (float*)alloc((size_t)n*4*4);
  int* rp     = (int*)alloc((size_t)(n+1)*4);
  int* fill   = (int*)alloc((size_t)n*4);
  int* cnt    = (int*)alloc((size_t)n*4);
  int* colA   = (int*)alloc((size_t)E*4);         // 6.4 MB
  int* bsum   = (int*)alloc(512*4);
  int* boff   = (int*)alloc(512*4);
  float* psum = (float*)alloc(64*128*4);
  int* gstart = (int*)alloc(65*4);

  float* outlog = (float*)d_out;
  float* h3     = (float*)d_out + 64*10;

  hipMemsetAsync(cnt,  0, (size_t)n*4, stream);
  hipMemsetAsync(psum, 0, 64*128*4,    stream);

  int nb = (n + 255)/256;   // 391 <= 512
  k_hist   <<<(E+255)/256, 256, 0, stream>>>(dstp, cnt, E);
  k_scan1  <<<nb, 256, 0, stream>>>(cnt, rp, bsum, n);
  k_scan2  <<<1, 512, 0, stream>>>(bsum, boff, nb);
  k_scan3  <<<nb, 256, 0, stream>>>(rp, boff, fill, n, E);
  k_scatter<<<(E+255)/256, 256, 0, stream>>>(srcp, dstp, fill, colA, E);

  k_bounds<<<1, 128, 0, stream>>>(batch, gstart, n);

  const int GG = 512;  // 2 blocks/CU resident
  // layer 1
  k_gemm_att<<<GG, 256, 0, stream>>>(x, W[0], al[0], ar[0], xw, ALb, ARb, n);
  k_attn<<<(n+3)/4, 256, 0, stream>>>(xw, ALb, ARb, rp, colA, bs[0], hbuf, n);
  // layer 2
  k_gemm_att<<<GG, 256, 0, stream>>>(hbuf, W[1], al[1], ar[1], xw, ALb, ARb, n);
  k_attn<<<(n+3)/4, 256, 0, stream>>>(xw, ALb, ARb, rp, colA, bs[1], hbuf, n);
  // layer 3 -> write h3 straight into d_out
  k_gemm_att<<<GG, 256, 0, stream>>>(hbuf, W[2], al[2], ar[2], xw, ALb, ARb, n);
  k_attn<<<(n+3)/4, 256, 0, stream>>>(xw, ALb, ARb, rp, colA, bs[2], h3, n);

  k_pool<<<64*8, 128, 0, stream>>>(h3, gstart, psum);
  k_mlp <<<64, 128, 0, stream>>>(psum, gstart, l1w, l1b, l2w, l2b, outlog);
}

// Round 4
// 823.195 us; speedup vs baseline: 2.1267x; 1.4211x over previous
//
#include <hip/hip_runtime.h>
#include <math.h>

// GAT 3-layer, MI355X. Round 3: single-sweep fused attention.
// - no max-subtraction (logits bounded; alpha = e/z is shift-invariant)
// - unnormalized accumulation, divide by z at end
// - per-64-edge chunk: lanes compute exp for distinct edges (1x, not 16x),
//   stage e + src in LDS, serial gather loop reads via LDS broadcast.

#define LRELU(x) ((x) > 0.f ? (x) : 0.2f*(x))

__device__ inline unsigned short f2bf(float f){
  unsigned u = __float_as_uint(f);
  u += 0x7fff + ((u >> 16) & 1);   // round-to-nearest-even
  return (unsigned short)(u >> 16);
}

// ---------------- CSR build ----------------
__global__ void k_hist(const int* __restrict__ dst, int* __restrict__ cnt, int E){
  int i = blockIdx.x*blockDim.x + threadIdx.x;
  if (i < E) atomicAdd(&cnt[dst[i]], 1);
}

__global__ void k_scan1(const int* __restrict__ cnt, int* __restrict__ rp,
                        int* __restrict__ bsum, int n){
  __shared__ int sh[256];
  int t = threadIdx.x, i = blockIdx.x*256 + t;
  int v = (i < n) ? cnt[i] : 0;
  sh[t] = v; __syncthreads();
  for (int off = 1; off < 256; off <<= 1){
    int x = (t >= off) ? sh[t-off] : 0;
    __syncthreads();
    sh[t] += x;
    __syncthreads();
  }
  if (i < n) rp[i] = sh[t] - v;          // exclusive within block
  if (t == 255) bsum[blockIdx.x] = sh[t];
}

__global__ void k_scan2(const int* __restrict__ bsum, int* __restrict__ boff, int nb){
  __shared__ int sh[512];
  int t = threadIdx.x;
  int v = (t < nb) ? bsum[t] : 0;
  sh[t] = v; __syncthreads();
  for (int off = 1; off < 512; off <<= 1){
    int x = (t >= off) ? sh[t-off] : 0;
    __syncthreads();
    sh[t] += x;
    __syncthreads();
  }
  if (t < nb) boff[t] = sh[t] - v;
}

__global__ void k_scan3(int* __restrict__ rp, const int* __restrict__ boff,
                        int* __restrict__ fill, int n, int total){
  int i = blockIdx.x*256 + threadIdx.x;
  if (i < n){
    int v = rp[i] + boff[blockIdx.x];
    rp[i] = v; fill[i] = v;
  }
  if (i == 0) rp[n] = total;
}

__global__ void k_scatter(const int* __restrict__ src, const int* __restrict__ dst,
                          int* __restrict__ fill, int* __restrict__ col, int E){
  int i = blockIdx.x*blockDim.x + threadIdx.x;
  if (i < E){
    int pos = atomicAdd(&fill[dst[i]], 1);
    col[pos] = src[i];
  }
}

// ---------------- graph boundaries via binary search (batch is sorted) ----
__global__ void k_bounds(const int* __restrict__ batch, int* __restrict__ gstart, int n){
  int g = threadIdx.x;
  if (g > 64) return;
  int lo = 0, hi = n;
  while (lo < hi){
    int mid = (lo + hi) >> 1;
    if (batch[mid] < g) lo = mid + 1; else hi = mid;
  }
  gstart[g] = lo;   // first index with batch[i] >= g; gstart[64] = n
}

// ---------------- GEMM (x @ W) fused with al/ar epilogue ----------------
// Tile 16 rows x 128 cols; 256 threads, 2x4 microtile each. XW stored bf16.
__global__ __launch_bounds__(256) void k_gemm_att(
    const float* __restrict__ X, const float* __restrict__ W,
    const float* __restrict__ attl, const float* __restrict__ attr,
    unsigned short* __restrict__ XW, float* __restrict__ AL, float* __restrict__ AR, int n)
{
  __shared__ float Wl[128*128];
  __shared__ float Xl[16*132];     // pad 132 to break bank aliasing across rows
  int t = threadIdx.x;
  for (int i = t; i < 4096; i += 256) ((float4*)Wl)[i] = ((const float4*)W)[i];
  int cg = t & 31, rg = t >> 5;    // col group 0..31 (4 cols each), row group 0..7 (2 rows)
  float4 alv = ((const float4*)attl)[cg];
  float4 arv = ((const float4*)attr)[cg];
  int ntiles = n >> 4;             // n divisible by 16 (100000 = 16*6250)
  for (int tile = blockIdx.x; tile < ntiles; tile += gridDim.x){
    int row0 = tile << 4;
    __syncthreads();               // protect Xl (and W on first iter)
    for (int i = t; i < 512; i += 256){
      int r = i >> 5, kk = i & 31;
      float4 v = ((const float4*)(X + (size_t)(row0+r)*128))[kk];
      *((float4*)&Xl[r*132 + kk*4]) = v;
    }
    __syncthreads();
    float acc[2][4] = {{0,0,0,0},{0,0,0,0}};
    int r0 = rg*2;
    const float* x0p = &Xl[r0*132];
    const float* x1p = &Xl[(r0+1)*132];
    #pragma unroll 8
    for (int k = 0; k < 128; k++){
      float4 wv = *((const float4*)&Wl[k*128 + cg*4]);
      float x0 = x0p[k], x1 = x1p[k];
      acc[0][0] = fmaf(x0, wv.x, acc[0][0]);
      acc[0][1] = fmaf(x0, wv.y, acc[0][1]);
      acc[0][2] = fmaf(x0, wv.z, acc[0][2]);
      acc[0][3] = fmaf(x0, wv.w, acc[0][3]);
      acc[1][0] = fmaf(x1, wv.x, acc[1][0]);
      acc[1][1] = fmaf(x1, wv.y, acc[1][1]);
      acc[1][2] = fmaf(x1, wv.z, acc[1][2]);
      acc[1][3] = fmaf(x1, wv.w, acc[1][3]);
    }
    int head = cg >> 3;            // cols cg*4..cg*4+3 all in head cg/8
    #pragma unroll
    for (int i = 0; i < 2; i++){
      int row = row0 + r0 + i;
      ushort4 o;
      o.x = f2bf(acc[i][0]); o.y = f2bf(acc[i][1]);
      o.z = f2bf(acc[i][2]); o.w = f2bf(acc[i][3]);
      ((ushort4*)(XW + (size_t)row*128))[cg] = o;
      float pl = acc[i][0]*alv.x + acc[i][1]*alv.y + acc[i][2]*alv.z + acc[i][3]*alv.w;
      float pr = acc[i][0]*arv.x + acc[i][1]*arv.y + acc[i][2]*arv.z + acc[i][3]*arv.w;
      // reduce over the 8 col-groups of one head (8 consecutive lanes)
      pl += __shfl_xor(pl, 4, 8); pl += __shfl_xor(pl, 2, 8); pl += __shfl_xor(pl, 1, 8);
      pr += __shfl_xor(pr, 4, 8); pr += __shfl_xor(pr, 2, 8); pr += __shfl_xor(pr, 1, 8);
      if ((cg & 7) == 0){ AL[row*4 + head] = pl; AR[row*4 + head] = pr; }
    }
  }
}

// ---------------- Attention + aggregate: one wave per dst, single sweep ----
__global__ __launch_bounds__(256) void k_attn(
    const unsigned short* __restrict__ XW, const float* __restrict__ AL, const float* __restrict__ AR,
    const int* __restrict__ rp, const int* __restrict__ col,
    const float* __restrict__ bias, float* __restrict__ OUT, int n)
{
  __shared__ float ebuf[4][64*4];   // per-wave: exp weights, layout [edge*4+head]
  __shared__ int   sbuf[4][64];     // per-wave: src indices
  int wv = threadIdx.x >> 6;
  int d = blockIdx.x*4 + wv;
  int lane = threadIdx.x & 63;
  if (d >= n) return;
  int start = rp[d], end = rp[d+1];
  float4 ald4 = ((const float4*)AL)[d];
  float4 ard4 = ((const float4*)AR)[d];
  float ar0 = ard4.x, ar1 = ard4.y, ar2 = ard4.z, ar3 = ard4.w;
  // self-loop unnormalized weights (wave-uniform)
  float es0 = __expf(LRELU(ald4.x + ar0));
  float es1 = __expf(LRELU(ald4.y + ar1));
  float es2 = __expf(LRELU(ald4.z + ar2));
  float es3 = __expf(LRELU(ald4.w + ar3));
  int h = lane >> 4;                // head owned in the gather loop
  float eself = h==0?es0 : h==1?es1 : h==2?es2 : es3;
  const unsigned* XWr = (const unsigned*)XW;  // one uint = 2 bf16 channels
  unsigned v = XWr[(size_t)d*64 + lane];
  float acc0 = eself * __uint_as_float(v << 16);
  float acc1 = eself * __uint_as_float(v & 0xffff0000u);
  float zl0 = 0.f, zl1 = 0.f, zl2 = 0.f, zl3 = 0.f;  // per-lane partial z
  float* eb = ebuf[wv];
  int*   sb = sbuf[wv];
  for (int base = start; base < end; base += 64){
    int cnt = min(64, end - base);
    // parallel phase: each lane computes exp weights for one edge (4 heads)
    int s = (lane < cnt) ? col[base + lane] : 0;
    float4 a = ((const float4*)AL)[s];
    float w0 = __expf(LRELU(a.x + ar0));
    float w1 = __expf(LRELU(a.y + ar1));
    float w2 = __expf(LRELU(a.z + ar2));
    float w3 = __expf(LRELU(a.w + ar3));
    if (lane >= cnt){ w0 = w1 = w2 = w3 = 0.f; }
    zl0 += w0; zl1 += w1; zl2 += w2; zl3 += w3;
    float4 w4; w4.x = w0; w4.y = w1; w4.z = w2; w4.w = w3;
    ((float4*)eb)[lane] = w4;       // banks: lane*4+h -> conflict-free reads
    sb[lane] = s;
    // serial gather phase (wave-synchronous: single instruction stream,
    // compiler inserts lgkmcnt waits for the LDS read-after-write)
    #pragma unroll 4
    for (int j = 0; j < cnt; j++){
      int sj = sb[j];               // broadcast
      float w = eb[j*4 + h];        // 4 distinct banks, 16-lane broadcast
      unsigned u = XWr[(size_t)sj*64 + lane];   // 256B contiguous gather
      acc0 = fmaf(w, __uint_as_float(u << 16), acc0);
      acc1 = fmaf(w, __uint_as_float(u & 0xffff0000u), acc1);
    }
  }
  // reduce z across the wave, add self term
  #pragma unroll
  for (int off = 32; off >= 1; off >>= 1){
    zl0 += __shfl_xor(zl0, off, 64);
    zl1 += __shfl_xor(zl1, off, 64);
    zl2 += __shfl_xor(zl2, off, 64);
    zl3 += __shfl_xor(zl3, off, 64);
  }
  float z_h = (h==0?zl0 : h==1?zl1 : h==2?zl2 : zl3) + eself;
  float rz = 1.f / z_h;
  int ch = lane*2;
  float o0 = fmaf(acc0, rz, bias[ch]);
  float o1 = fmaf(acc1, rz, bias[ch+1]);
  o0 = o0 > 0.f ? o0 : 0.f;   // relu after every GAT layer per reference
  o1 = o1 > 0.f ? o1 : 0.f;
  float2 o; o.x = o0; o.y = o1;
  ((float2*)(OUT + (size_t)d*128))[lane] = o;
}

// ---------------- pooling + MLP head ----------------
__global__ __launch_bounds__(128) void k_pool(const float* __restrict__ H,
                                              const int* __restrict__ gstart,
                                              float* __restrict__ psum){
  int g = blockIdx.x >> 3, slice = blockIdx.x & 7, t = threadIdx.x;
  int s0 = gstart[g], s1 = gstart[g+1];
  int cntg = s1 - s0;
  int chunk = (cntg + 7) >> 3;
  int lo = s0 + slice*chunk;
  int hi = min(lo + chunk, s1);
  float sum = 0.f;
  for (int i = lo; i < hi; i++) sum += H[(size_t)i*128 + t];
  atomicAdd(&psum[g*128 + t], sum);
}

__global__ __launch_bounds__(128) void k_mlp(const float* __restrict__ psum,
                       const int* __restrict__ gstart,
                       const float* __restrict__ w1, const float* __restrict__ b1,
                       const float* __restrict__ w2, const float* __restrict__ b2,
                       float* __restrict__ out)
{
  __shared__ float p[128];
  __shared__ float gsh[128];
  __shared__ float lg[10];
  int g = blockIdx.x, t = threadIdx.x;
  float c = fmaxf((float)(gstart[g+1] - gstart[g]), 1.f);
  p[t] = psum[g*128 + t] / c;
  __syncthreads();
  float acc = b1[t];
  for (int k = 0; k < 128; k++) acc = fmaf(p[k], w1[k*128 + t], acc);
  gsh[t] = acc > 0.f ? acc : 0.f;
  __syncthreads();
  if (t < 10){
    float a = b2[t];
    for (int k = 0; k < 128; k++) a = fmaf(gsh[k], w2[k*10 + t], a);
    lg[t] = a;
  }
  __syncthreads();
  if (t < 10){
    float mx = lg[0];
    for (int c2 = 1; c2 < 10; c2++) mx = fmaxf(mx, lg[c2]);
    float se = 0.f;
    for (int c2 = 0; c2 < 10; c2++) se += __expf(lg[c2] - mx);
    out[g*10 + t] = lg[t] - mx - logf(se);
  }
}

extern "C" void kernel_launch(void* const* d_in, const int* in_sizes, int n_in,
                              void* d_out, int out_size, void* d_ws, size_t ws_size,
                              hipStream_t stream)
{
  const float* x    = (const float*)d_in[0];
  const int* eidx   = (const int*)d_in[1];
  const int* batch  = (const int*)d_in[2];
  const float* W[3]  = {(const float*)d_in[3], (const float*)d_in[7],  (const float*)d_in[11]};
  const float* al[3] = {(const float*)d_in[4], (const float*)d_in[8],  (const float*)d_in[12]};
  const float* ar[3] = {(const float*)d_in[5], (const float*)d_in[9],  (const float*)d_in[13]};
  const float* bs[3] = {(const float*)d_in[6], (const float*)d_in[10], (const float*)d_in[14]};
  const float* l1w = (const float*)d_in[15];
  const float* l1b = (const float*)d_in[16];
  const float* l2w = (const float*)d_in[17];
  const float* l2b = (const float*)d_in[18];
  int E = in_sizes[1] / 2;
  int n = in_sizes[2];            // N_NODES = 100000 (divisible by 16)
  const int* srcp = eidx;
  const int* dstp = eidx + E;

  char* wsp = (char*)d_ws;
  auto alloc = [&](size_t bytes){ void* p = (void*)wsp; wsp += (bytes + 255) & ~(size_t)255; return p; };
  unsigned short* xw = (unsigned short*)alloc((size_t)n*128*2);  // 25.6 MB bf16
  float* hbuf = (float*)alloc((size_t)n*128*4);   // 51.2 MB
  float* ALb  = (float*)alloc((size_t)n*4*4);
  float* ARb  = (float*)alloc((size_t)n*4*4);
  int* rp     = (int*)alloc((size_t)(n+1)*4);
  int* fill   = (int*)alloc((size_t)n*4);
  int* cnt    = (int*)alloc((size_t)n*4);
  int* colA   = (int*)alloc((size_t)E*4);         // 6.4 MB
  int* bsum   = (int*)alloc(512*4);
  int* boff   = (int*)alloc(512*4);
  float* psum = (float*)alloc(64*128*4);
  int* gstart = (int*)alloc(65*4);

  float* outlog = (float*)d_out;
  float* h3     = (float*)d_out + 64*10;

  hipMemsetAsync(cnt,  0, (size_t)n*4, stream);
  hipMemsetAsync(psum, 0, 64*128*4,    stream);

  int nb = (n + 255)/256;   // 391 <= 512
  k_hist   <<<(E+255)/256, 256, 0, stream>>>(dstp, cnt, E);
  k_scan1  <<<nb, 256, 0, stream>>>(cnt, rp, bsum, n);
  k_scan2  <<<1, 512, 0, stream>>>(bsum, boff, nb);
  k_scan3  <<<nb, 256, 0, stream>>>(rp, boff, fill, n, E);
  k_scatter<<<(E+255)/256, 256, 0, stream>>>(srcp, dstp, fill, colA, E);

  k_bounds<<<1, 128, 0, stream>>>(batch, gstart, n);

  const int GG = 512;  // 2 blocks/CU resident
  // layer 1
  k_gemm_att<<<GG, 256, 0, stream>>>(x, W[0], al[0], ar[0], xw, ALb, ARb, n);
  k_attn<<<(n+3)/4, 256, 0, stream>>>(xw, ALb, ARb, rp, colA, bs[0], hbuf, n);
  // layer 2
  k_gemm_att<<<GG, 256, 0, stream>>>(hbuf, W[1], al[1], ar[1], xw, ALb, ARb, n);
  k_attn<<<(n+3)/4, 256, 0, stream>>>(xw, ALb, ARb, rp, colA, bs[1], hbuf, n);
  // layer 3 -> write h3 straight into d_out
  k_gemm_att<<<GG, 256, 0, stream>>>(hbuf, W[2], al[2], ar[2], xw, ALb, ARb, n);
  k_attn<<<(n+3)/4, 256, 0, stream>>>(xw, ALb, ARb, rp, colA, bs[2], h3, n);

  k_pool<<<64*8, 128, 0, stream>>>(h3, gstart, psum);
  k_mlp <<<64, 128, 0, stream>>>(psum, gstart, l1w, l1b, l2w, l2b, outlog);
}

// Round 5
// 760.053 us; speedup vs baseline: 2.3034x; 1.0831x over previous
//
#include <hip/hip_runtime.h>
#include <math.h>

// GAT 3-layer, MI355X. Round 4:
// (1) CSR build rewritten: bucket histogram + LDS multi-split partition +
//     per-bucket CSR (one CU per 8KB col window -> L2 write merging).
//     Replaces hist/scan1-3/scatter (105MB of unmerged scattered writes).
// (2) hidden activations h (layers 1-2) stored bf16.

#define LRELU(x) ((x) > 0.f ? (x) : 0.2f*(x))
#define SH 7          // bucket = dst >> 7 (128 nodes per bucket)
#define TILE 4096
#define EPT 16

__device__ inline unsigned short f2bf(float f){
  unsigned u = __float_as_uint(f);
  u += 0x7fff + ((u >> 16) & 1);   // round-to-nearest-even
  return (unsigned short)(u >> 16);
}

// ---------------- CSR build: bucketed two-pass ----------------
__global__ void k_bcnt(const int* __restrict__ dst, int* __restrict__ bcntP, int E){
  int i = blockIdx.x*256 + threadIdx.x;
  if (i < E) atomicAdd(&bcntP[(dst[i] >> SH) * 16], 1);   // 1 counter per 64B line
}

__global__ __launch_bounds__(256) void k_bscan(const int* __restrict__ bcntP,
    int* __restrict__ bstart, int* __restrict__ bfill, int NB, int E){
  __shared__ int c[1024];
  __shared__ int ps[256];
  int t = threadIdx.x;
  for (int j = t; j < 1024; j += 256) c[j] = (j < NB) ? bcntP[j*16] : 0;
  __syncthreads();
  int b0 = 4*t;
  int v0=c[b0], v1=c[b0+1], v2=c[b0+2], v3=c[b0+3];
  int e1=v0, e2=v0+v1, e3=e2+v2, ts=e3+v3;
  ps[t] = ts; __syncthreads();
  for (int off=1; off<256; off<<=1){
    int x = (t>=off) ? ps[t-off] : 0; __syncthreads();
    ps[t] += x; __syncthreads();
  }
  int pre = ps[t] - ts;
  int ex0=pre, ex1=pre+e1, ex2=pre+e2, ex3=pre+e3;
  if (b0   < NB){ bstart[b0]=ex0;   bfill[b0]=ex0; }
  if (b0+1 < NB){ bstart[b0+1]=ex1; bfill[b0+1]=ex1; }
  if (b0+2 < NB){ bstart[b0+2]=ex2; bfill[b0+2]=ex2; }
  if (b0+3 < NB){ bstart[b0+3]=ex3; bfill[b0+3]=ex3; }
  if (t == 0) bstart[NB] = E;
}

// LDS multi-split: tile of 4096 edges ranked by bucket, flushed as
// bucket-contiguous runs (coalesced writes vs 1.6M isolated dwords).
__global__ __launch_bounds__(256) void k_part(const int* __restrict__ src,
    const int* __restrict__ dst, int* __restrict__ bfill,
    int2* __restrict__ tmp, int E){
  __shared__ int2 reorder[TILE];
  __shared__ int lhist[1024], lscan[1024], lgbase[1024];
  __shared__ int ps[256];
  int t = threadIdx.x;
  int tb = blockIdx.x * TILE;
  int tilecnt = min(TILE, E - tb);
  for (int j = t; j < 1024; j += 256) lhist[j] = 0;
  __syncthreads();
  int ss[EPT], dd[EPT], rk[EPT];
  #pragma unroll
  for (int i = 0; i < EPT; i++){
    int e = tb + t + i*256;
    if (e < E){
      ss[i] = src[e]; dd[i] = dst[e];
      rk[i] = atomicAdd(&lhist[dd[i] >> SH], 1);
    }
  }
  __syncthreads();
  int b0 = 4*t;
  int v0=lhist[b0], v1=lhist[b0+1], v2=lhist[b0+2], v3=lhist[b0+3];
  int e1=v0, e2=v0+v1, e3=e2+v2, ts=e3+v3;
  ps[t] = ts; __syncthreads();
  for (int off=1; off<256; off<<=1){
    int x = (t>=off) ? ps[t-off] : 0; __syncthreads();
    ps[t] += x; __syncthreads();
  }
  int pre = ps[t] - ts;
  int ex[4] = {pre, pre+e1, pre+e2, pre+e3};
  lscan[b0]=ex[0]; lscan[b0+1]=ex[1]; lscan[b0+2]=ex[2]; lscan[b0+3]=ex[3];
  int cb[4] = {v0, v1, v2, v3};
  #pragma unroll
  for (int i = 0; i < 4; i++){
    if (cb[i] > 0){
      int gb = atomicAdd(&bfill[b0+i], cb[i]);
      lgbase[b0+i] = gb - ex[i];
    }
  }
  __syncthreads();
  #pragma unroll
  for (int i = 0; i < EPT; i++){
    int e = tb + t + i*256;
    if (e < E){
      int b = dd[i] >> SH;
      reorder[lscan[b] + rk[i]] = make_int2(ss[i], dd[i]);
    }
  }
  __syncthreads();
  for (int j = t; j < tilecnt; j += 256){
    int2 p = reorder[j];
    tmp[lgbase[p.y >> SH] + j] = p;
  }
}

// One block per bucket: per-node offsets via 128-wide LDS scan (writes rp),
// then scatter src into the bucket's ~8KB col window (single-CU -> merges).
__global__ __launch_bounds__(256) void k_csr(const int2* __restrict__ tmp,
    const int* __restrict__ bstart, int* __restrict__ rp, int* __restrict__ col,
    int n, int E){
  __shared__ int lcnt[128];
  __shared__ int sc[128];
  int b = blockIdx.x, t = threadIdx.x;
  int node0 = b << SH;
  int ncnt = min(128, n - node0);
  int be = bstart[b], ee = bstart[b+1];
  if (t < 128) lcnt[t] = 0;
  __syncthreads();
  for (int e = be + t; e < ee; e += 256)
    atomicAdd(&lcnt[tmp[e].y - node0], 1);
  __syncthreads();
  int v = (t < 128) ? lcnt[t] : 0;
  if (t < 128) sc[t] = v;
  __syncthreads();
  for (int off=1; off<128; off<<=1){
    int x = 0;
    if (t < 128 && t >= off) x = sc[t-off];
    __syncthreads();
    if (t < 128) sc[t] += x;
    __syncthreads();
  }
  if (t < 128){
    int start = be + sc[t] - v;    // exclusive
    lcnt[t] = start;               // reuse as fill pointer
    if (t < ncnt) rp[node0 + t] = start;
  }
  if (t == 0 && node0 + ncnt == n) rp[n] = E;
  __syncthreads();
  for (int e = be + t; e < ee; e += 256){
    int2 p = tmp[e];
    int pos = atomicAdd(&lcnt[p.y - node0], 1);
    col[pos] = p.x;
  }
}

// ---------------- graph boundaries via binary search (batch is sorted) ----
__global__ void k_bounds(const int* __restrict__ batch, int* __restrict__ gstart, int n){
  int g = threadIdx.x;
  if (g > 64) return;
  int lo = 0, hi = n;
  while (lo < hi){
    int mid = (lo + hi) >> 1;
    if (batch[mid] < g) lo = mid + 1; else hi = mid;
  }
  gstart[g] = lo;
}

// ---------------- GEMM (x @ W) fused with al/ar epilogue ----------------
// Tile 16 rows x 128 cols; 256 threads, 2x4 microtile. XW out bf16.
// BF16IN: X is bf16 (layers 2-3); else fp32 (layer 1).
template<bool BF16IN>
__global__ __launch_bounds__(256) void k_gemm_att(
    const void* __restrict__ Xv, const float* __restrict__ W,
    const float* __restrict__ attl, const float* __restrict__ attr,
    unsigned short* __restrict__ XW, float* __restrict__ AL, float* __restrict__ AR, int n)
{
  __shared__ float Wl[128*128];
  __shared__ float Xl[16*132];
  int t = threadIdx.x;
  for (int i = t; i < 4096; i += 256) ((float4*)Wl)[i] = ((const float4*)W)[i];
  int cg = t & 31, rg = t >> 5;
  float4 alv = ((const float4*)attl)[cg];
  float4 arv = ((const float4*)attr)[cg];
  int ntiles = n >> 4;
  for (int tile = blockIdx.x; tile < ntiles; tile += gridDim.x){
    int row0 = tile << 4;
    __syncthreads();
    if (BF16IN){
      int r = t >> 4, c8 = t & 15;   // 256 threads = 16 rows x 16 col-groups of 8
      const unsigned short* xrow = (const unsigned short*)Xv + (size_t)(row0+r)*128 + c8*8;
      uint4 u = *((const uint4*)xrow);
      float* dp = &Xl[r*132 + c8*8];
      dp[0] = __uint_as_float(u.x << 16); dp[1] = __uint_as_float(u.x & 0xffff0000u);
      dp[2] = __uint_as_float(u.y << 16); dp[3] = __uint_as_float(u.y & 0xffff0000u);
      dp[4] = __uint_as_float(u.z << 16); dp[5] = __uint_as_float(u.z & 0xffff0000u);
      dp[6] = __uint_as_float(u.w << 16); dp[7] = __uint_as_float(u.w & 0xffff0000u);
    } else {
      const float* X = (const float*)Xv;
      for (int i = t; i < 512; i += 256){
        int r = i >> 5, kk = i & 31;
        float4 v = ((const float4*)(X + (size_t)(row0+r)*128))[kk];
        *((float4*)&Xl[r*132 + kk*4]) = v;
      }
    }
    __syncthreads();
    float acc[2][4] = {{0,0,0,0},{0,0,0,0}};
    int r0 = rg*2;
    const float* x0p = &Xl[r0*132];
    const float* x1p = &Xl[(r0+1)*132];
    #pragma unroll 8
    for (int k = 0; k < 128; k++){
      float4 wv = *((const float4*)&Wl[k*128 + cg*4]);
      float x0 = x0p[k], x1 = x1p[k];
      acc[0][0] = fmaf(x0, wv.x, acc[0][0]);
      acc[0][1] = fmaf(x0, wv.y, acc[0][1]);
      acc[0][2] = fmaf(x0, wv.z, acc[0][2]);
      acc[0][3] = fmaf(x0, wv.w, acc[0][3]);
      acc[1][0] = fmaf(x1, wv.x, acc[1][0]);
      acc[1][1] = fmaf(x1, wv.y, acc[1][1]);
      acc[1][2] = fmaf(x1, wv.z, acc[1][2]);
      acc[1][3] = fmaf(x1, wv.w, acc[1][3]);
    }
    int head = cg >> 3;
    #pragma unroll
    for (int i = 0; i < 2; i++){
      int row = row0 + r0 + i;
      ushort4 o;
      o.x = f2bf(acc[i][0]); o.y = f2bf(acc[i][1]);
      o.z = f2bf(acc[i][2]); o.w = f2bf(acc[i][3]);
      ((ushort4*)(XW + (size_t)row*128))[cg] = o;
      float pl = acc[i][0]*alv.x + acc[i][1]*alv.y + acc[i][2]*alv.z + acc[i][3]*alv.w;
      float pr = acc[i][0]*arv.x + acc[i][1]*arv.y + acc[i][2]*arv.z + acc[i][3]*arv.w;
      pl += __shfl_xor(pl, 4, 8); pl += __shfl_xor(pl, 2, 8); pl += __shfl_xor(pl, 1, 8);
      pr += __shfl_xor(pr, 4, 8); pr += __shfl_xor(pr, 2, 8); pr += __shfl_xor(pr, 1, 8);
      if ((cg & 7) == 0){ AL[row*4 + head] = pl; AR[row*4 + head] = pr; }
    }
  }
}

// ---------------- Attention + aggregate: one wave per dst, single sweep ----
// BF16OUT: write h as packed bf16 (layers 1-2); else fp32 (layer 3 -> d_out).
template<bool BF16OUT>
__global__ __launch_bounds__(256) void k_attn(
    const unsigned short* __restrict__ XW, const float* __restrict__ AL, const float* __restrict__ AR,
    const int* __restrict__ rp, const int* __restrict__ col,
    const float* __restrict__ bias, void* __restrict__ OUT, int n)
{
  __shared__ float ebuf[4][64*4];
  __shared__ int   sbuf[4][64];
  int wv = threadIdx.x >> 6;
  int d = blockIdx.x*4 + wv;
  int lane = threadIdx.x & 63;
  if (d >= n) return;
  int start = rp[d], end = rp[d+1];
  float4 ald4 = ((const float4*)AL)[d];
  float4 ard4 = ((const float4*)AR)[d];
  float ar0 = ard4.x, ar1 = ard4.y, ar2 = ard4.z, ar3 = ard4.w;
  float es0 = __expf(LRELU(ald4.x + ar0));
  float es1 = __expf(LRELU(ald4.y + ar1));
  float es2 = __expf(LRELU(ald4.z + ar2));
  float es3 = __expf(LRELU(ald4.w + ar3));
  int h = lane >> 4;
  float eself = h==0?es0 : h==1?es1 : h==2?es2 : es3;
  const unsigned* XWr = (const unsigned*)XW;
  unsigned v = XWr[(size_t)d*64 + lane];
  float acc0 = eself * __uint_as_float(v << 16);
  float acc1 = eself * __uint_as_float(v & 0xffff0000u);
  float zl0 = 0.f, zl1 = 0.f, zl2 = 0.f, zl3 = 0.f;
  float* eb = ebuf[wv];
  int*   sb = sbuf[wv];
  for (int base = start; base < end; base += 64){
    int cnt = min(64, end - base);
    int s = (lane < cnt) ? col[base + lane] : 0;
    float4 a = ((const float4*)AL)[s];
    float w0 = __expf(LRELU(a.x + ar0));
    float w1 = __expf(LRELU(a.y + ar1));
    float w2 = __expf(LRELU(a.z + ar2));
    float w3 = __expf(LRELU(a.w + ar3));
    if (lane >= cnt){ w0 = w1 = w2 = w3 = 0.f; }
    zl0 += w0; zl1 += w1; zl2 += w2; zl3 += w3;
    float4 w4; w4.x = w0; w4.y = w1; w4.z = w2; w4.w = w3;
    ((float4*)eb)[lane] = w4;
    sb[lane] = s;
    #pragma unroll 4
    for (int j = 0; j < cnt; j++){
      int sj = sb[j];
      float w = eb[j*4 + h];
      unsigned u = XWr[(size_t)sj*64 + lane];
      acc0 = fmaf(w, __uint_as_float(u << 16), acc0);
      acc1 = fmaf(w, __uint_as_float(u & 0xffff0000u), acc1);
    }
  }
  #pragma unroll
  for (int off = 32; off >= 1; off >>= 1){
    zl0 += __shfl_xor(zl0, off, 64);
    zl1 += __shfl_xor(zl1, off, 64);
    zl2 += __shfl_xor(zl2, off, 64);
    zl3 += __shfl_xor(zl3, off, 64);
  }
  float z_h = (h==0?zl0 : h==1?zl1 : h==2?zl2 : zl3) + eself;
  float rz = 1.f / z_h;
  int ch = lane*2;
  float o0 = fmaf(acc0, rz, bias[ch]);
  float o1 = fmaf(acc1, rz, bias[ch+1]);
  o0 = o0 > 0.f ? o0 : 0.f;
  o1 = o1 > 0.f ? o1 : 0.f;
  if (BF16OUT){
    unsigned pk = (unsigned)f2bf(o0) | ((unsigned)f2bf(o1) << 16);
    ((unsigned*)OUT)[(size_t)d*64 + lane] = pk;
  } else {
    float2 o; o.x = o0; o.y = o1;
    ((float2*)OUT)[(size_t)d*64 + lane] = o;
  }
}

// ---------------- pooling + MLP head ----------------
__global__ __launch_bounds__(128) void k_pool(const float* __restrict__ H,
                                              const int* __restrict__ gstart,
                                              float* __restrict__ psum){
  int g = blockIdx.x >> 3, slice = blockIdx.x & 7, t = threadIdx.x;
  int s0 = gstart[g], s1 = gstart[g+1];
  int cntg = s1 - s0;
  int chunk = (cntg + 7) >> 3;
  int lo = s0 + slice*chunk;
  int hi = min(lo + chunk, s1);
  float sum = 0.f;
  for (int i = lo; i < hi; i++) sum += H[(size_t)i*128 + t];
  atomicAdd(&psum[g*128 + t], sum);
}

__global__ __launch_bounds__(128) void k_mlp(const float* __restrict__ psum,
                       const int* __restrict__ gstart,
                       const float* __restrict__ w1, const float* __restrict__ b1,
                       const float* __restrict__ w2, const float* __restrict__ b2,
                       float* __restrict__ out)
{
  __shared__ float p[128];
  __shared__ float gsh[128];
  __shared__ float lg[10];
  int g = blockIdx.x, t = threadIdx.x;
  float c = fmaxf((float)(gstart[g+1] - gstart[g]), 1.f);
  p[t] = psum[g*128 + t] / c;
  __syncthreads();
  float acc = b1[t];
  for (int k = 0; k < 128; k++) acc = fmaf(p[k], w1[k*128 + t], acc);
  gsh[t] = acc > 0.f ? acc : 0.f;
  __syncthreads();
  if (t < 10){
    float a = b2[t];
    for (int k = 0; k < 128; k++) a = fmaf(gsh[k], w2[k*10 + t], a);
    lg[t] = a;
  }
  __syncthreads();
  if (t < 10){
    float mx = lg[0];
    for (int c2 = 1; c2 < 10; c2++) mx = fmaxf(mx, lg[c2]);
    float se = 0.f;
    for (int c2 = 0; c2 < 10; c2++) se += __expf(lg[c2] - mx);
    out[g*10 + t] = lg[t] - mx - logf(se);
  }
}

extern "C" void kernel_launch(void* const* d_in, const int* in_sizes, int n_in,
                              void* d_out, int out_size, void* d_ws, size_t ws_size,
                              hipStream_t stream)
{
  const float* x    = (const float*)d_in[0];
  const int* eidx   = (const int*)d_in[1];
  const int* batch  = (const int*)d_in[2];
  const float* W[3]  = {(const float*)d_in[3], (const float*)d_in[7],  (const float*)d_in[11]};
  const float* al[3] = {(const float*)d_in[4], (const float*)d_in[8],  (const float*)d_in[12]};
  const float* ar[3] = {(const float*)d_in[5], (const float*)d_in[9],  (const float*)d_in[13]};
  const float* bs[3] = {(const float*)d_in[6], (const float*)d_in[10], (const float*)d_in[14]};
  const float* l1w = (const float*)d_in[15];
  const float* l1b = (const float*)d_in[16];
  const float* l2w = (const float*)d_in[17];
  const float* l2b = (const float*)d_in[18];
  int E = in_sizes[1] / 2;
  int n = in_sizes[2];            // 100000
  const int* srcp = eidx;
  const int* dstp = eidx + E;
  int NB = (n + 127) >> SH;       // 782 buckets (<=1024)

  char* wsp = (char*)d_ws;
  auto alloc = [&](size_t bytes){ void* p = (void*)wsp; wsp += (bytes + 255) & ~(size_t)255; return p; };
  unsigned short* xw   = (unsigned short*)alloc((size_t)n*128*2);  // 25.6 MB bf16
  unsigned short* hbuf = (unsigned short*)alloc((size_t)n*128*2);  // 25.6 MB bf16
  float* ALb  = (float*)alloc((size_t)n*4*4);
  float* ARb  = (float*)alloc((size_t)n*4*4);
  int* rp     = (int*)alloc((size_t)(n+1)*4);
  int* col    = (int*)alloc((size_t)E*4);          // 6.4 MB
  int2* tmp   = (int2*)alloc((size_t)E*8);         // 12.8 MB bucketed pairs
  int* bcntP  = (int*)alloc(1024*16*4);            // line-padded counters
  int* bstart = (int*)alloc(1025*4);
  int* bfill  = (int*)alloc(1024*4);
  float* psum = (float*)alloc(64*128*4);
  int* gstart = (int*)alloc(65*4);

  float* outlog = (float*)d_out;
  float* h3     = (float*)d_out + 64*10;

  hipMemsetAsync(bcntP, 0, 1024*16*4, stream);
  hipMemsetAsync(psum,  0, 64*128*4,  stream);

  // CSR build
  k_bcnt <<<(E+255)/256, 256, 0, stream>>>(dstp, bcntP, E);
  k_bscan<<<1, 256, 0, stream>>>(bcntP, bstart, bfill, NB, E);
  k_part <<<(E+TILE-1)/TILE, 256, 0, stream>>>(srcp, dstp, bfill, tmp, E);
  k_csr  <<<NB, 256, 0, stream>>>(tmp, bstart, rp, col, n, E);

  k_bounds<<<1, 128, 0, stream>>>(batch, gstart, n);

  const int GG = 512;
  // layer 1 (fp32 in, bf16 h out)
  k_gemm_att<false><<<GG, 256, 0, stream>>>(x, W[0], al[0], ar[0], xw, ALb, ARb, n);
  k_attn<true><<<(n+3)/4, 256, 0, stream>>>(xw, ALb, ARb, rp, col, bs[0], hbuf, n);
  // layer 2 (bf16 in, bf16 h out)
  k_gemm_att<true><<<GG, 256, 0, stream>>>(hbuf, W[1], al[1], ar[1], xw, ALb, ARb, n);
  k_attn<true><<<(n+3)/4, 256, 0, stream>>>(xw, ALb, ARb, rp, col, bs[1], hbuf, n);
  // layer 3 (bf16 in, fp32 out straight into d_out)
  k_gemm_att<true><<<GG, 256, 0, stream>>>(hbuf, W[2], al[2], ar[2], xw, ALb, ARb, n);
  k_attn<false><<<(n+3)/4, 256, 0, stream>>>(xw, ALb, ARb, rp, col, bs[2], h3, n);

  k_pool<<<64*8, 128, 0, stream>>>(h3, gstart, psum);
  k_mlp <<<64, 128, 0, stream>>>(psum, gstart, l1w, l1b, l2w, l2b, outlog);
}

// Round 6
// 599.838 us; speedup vs baseline: 2.9187x; 1.2671x over previous
//
#include <hip/hip_runtime.h>
#include <math.h>

// GAT 3-layer, MI355X. Round 5:
// (1) GEMM -> MFMA bf16 (16x16x32), LDS-roundtrip epilogue (coalesced xw
//     store + local per-head al/ar dot, no shuffles).
// (2) k_bcnt -> LDS histogram (removes 1.6M contended global atomics).

#define LRELU(x) ((x) > 0.f ? (x) : 0.2f*(x))
#define SH 7          // bucket = dst >> 7 (128 nodes per bucket)
#define TILE 4096
#define EPT 16

typedef __attribute__((ext_vector_type(8))) short s16x8;
typedef __attribute__((ext_vector_type(4))) float f32x4;

__device__ inline unsigned short f2bf(float f){
  unsigned u = __float_as_uint(f);
  u += 0x7fff + ((u >> 16) & 1);   // round-to-nearest-even
  return (unsigned short)(u >> 16);
}

// ---------------- CSR build: bucketed two-pass ----------------
__global__ __launch_bounds__(256) void k_bcnt(const int* __restrict__ dst,
    int* __restrict__ bcnt, int E, int NB){
  __shared__ int lh[1024];
  int t = threadIdx.x;
  for (int j = t; j < 1024; j += 256) lh[j] = 0;
  __syncthreads();
  int base = blockIdx.x * TILE;
  int lim = min(base + TILE, E);
  for (int e = base + t; e < lim; e += 256)
    atomicAdd(&lh[dst[e] >> SH], 1);
  __syncthreads();
  for (int j = t; j < NB; j += 256){
    int v = lh[j];
    if (v) atomicAdd(&bcnt[j], v);
  }
}

__global__ __launch_bounds__(256) void k_bscan(const int* __restrict__ bcnt,
    int* __restrict__ bstart, int* __restrict__ bfill, int NB, int E){
  __shared__ int c[1024];
  __shared__ int ps[256];
  int t = threadIdx.x;
  for (int j = t; j < 1024; j += 256) c[j] = (j < NB) ? bcnt[j] : 0;
  __syncthreads();
  int b0 = 4*t;
  int v0=c[b0], v1=c[b0+1], v2=c[b0+2], v3=c[b0+3];
  int e1=v0, e2=v0+v1, e3=e2+v2, ts=e3+v3;
  ps[t] = ts; __syncthreads();
  for (int off=1; off<256; off<<=1){
    int x = (t>=off) ? ps[t-off] : 0; __syncthreads();
    ps[t] += x; __syncthreads();
  }
  int pre = ps[t] - ts;
  int ex0=pre, ex1=pre+e1, ex2=pre+e2, ex3=pre+e3;
  if (b0   < NB){ bstart[b0]=ex0;   bfill[b0]=ex0; }
  if (b0+1 < NB){ bstart[b0+1]=ex1; bfill[b0+1]=ex1; }
  if (b0+2 < NB){ bstart[b0+2]=ex2; bfill[b0+2]=ex2; }
  if (b0+3 < NB){ bstart[b0+3]=ex3; bfill[b0+3]=ex3; }
  if (t == 0) bstart[NB] = E;
}

// LDS multi-split: tile of 4096 edges ranked by bucket, flushed as
// bucket-contiguous runs (coalesced writes vs 1.6M isolated dwords).
__global__ __launch_bounds__(256) void k_part(const int* __restrict__ src,
    const int* __restrict__ dst, int* __restrict__ bfill,
    int2* __restrict__ tmp, int E){
  __shared__ int2 reorder[TILE];
  __shared__ int lhist[1024], lscan[1024], lgbase[1024];
  __shared__ int ps[256];
  int t = threadIdx.x;
  int tb = blockIdx.x * TILE;
  int tilecnt = min(TILE, E - tb);
  for (int j = t; j < 1024; j += 256) lhist[j] = 0;
  __syncthreads();
  int ss[EPT], dd[EPT], rk[EPT];
  #pragma unroll
  for (int i = 0; i < EPT; i++){
    int e = tb + t + i*256;
    if (e < E){
      ss[i] = src[e]; dd[i] = dst[e];
      rk[i] = atomicAdd(&lhist[dd[i] >> SH], 1);
    }
  }
  __syncthreads();
  int b0 = 4*t;
  int v0=lhist[b0], v1=lhist[b0+1], v2=lhist[b0+2], v3=lhist[b0+3];
  int e1=v0, e2=v0+v1, e3=e2+v2, ts=e3+v3;
  ps[t] = ts; __syncthreads();
  for (int off=1; off<256; off<<=1){
    int x = (t>=off) ? ps[t-off] : 0; __syncthreads();
    ps[t] += x; __syncthreads();
  }
  int pre = ps[t] - ts;
  int ex[4] = {pre, pre+e1, pre+e2, pre+e3};
  lscan[b0]=ex[0]; lscan[b0+1]=ex[1]; lscan[b0+2]=ex[2]; lscan[b0+3]=ex[3];
  int cb[4] = {v0, v1, v2, v3};
  #pragma unroll
  for (int i = 0; i < 4; i++){
    if (cb[i] > 0){
      int gb = atomicAdd(&bfill[b0+i], cb[i]);
      lgbase[b0+i] = gb - ex[i];
    }
  }
  __syncthreads();
  #pragma unroll
  for (int i = 0; i < EPT; i++){
    int e = tb + t + i*256;
    if (e < E){
      int b = dd[i] >> SH;
      reorder[lscan[b] + rk[i]] = make_int2(ss[i], dd[i]);
    }
  }
  __syncthreads();
  for (int j = t; j < tilecnt; j += 256){
    int2 p = reorder[j];
    tmp[lgbase[p.y >> SH] + j] = p;
  }
}

// One block per bucket: per-node offsets via 128-wide LDS scan (writes rp),
// then scatter src into the bucket's ~8KB col window (single-CU -> merges).
__global__ __launch_bounds__(256) void k_csr(const int2* __restrict__ tmp,
    const int* __restrict__ bstart, int* __restrict__ rp, int* __restrict__ col,
    int n, int E){
  __shared__ int lcnt[128];
  __shared__ int sc[128];
  int b = blockIdx.x, t = threadIdx.x;
  int node0 = b << SH;
  int ncnt = min(128, n - node0);
  int be = bstart[b], ee = bstart[b+1];
  if (t < 128) lcnt[t] = 0;
  __syncthreads();
  for (int e = be + t; e < ee; e += 256)
    atomicAdd(&lcnt[tmp[e].y - node0], 1);
  __syncthreads();
  int v = (t < 128) ? lcnt[t] : 0;
  if (t < 128) sc[t] = v;
  __syncthreads();
  for (int off=1; off<128; off<<=1){
    int x = 0;
    if (t < 128 && t >= off) x = sc[t-off];
    __syncthreads();
    if (t < 128) sc[t] += x;
    __syncthreads();
  }
  if (t < 128){
    int start = be + sc[t] - v;
    lcnt[t] = start;
    if (t < ncnt) rp[node0 + t] = start;
  }
  if (t == 0 && node0 + ncnt == n) rp[n] = E;
  __syncthreads();
  for (int e = be + t; e < ee; e += 256){
    int2 p = tmp[e];
    int pos = atomicAdd(&lcnt[p.y - node0], 1);
    col[pos] = p.x;
  }
}

// ---------------- graph boundaries via binary search (batch is sorted) ----
__global__ void k_bounds(const int* __restrict__ batch, int* __restrict__ gstart, int n){
  int g = threadIdx.x;
  if (g > 64) return;
  int lo = 0, hi = n;
  while (lo < hi){
    int mid = (lo + hi) >> 1;
    if (batch[mid] < g) lo = mid + 1; else hi = mid;
  }
  gstart[g] = lo;
}

// ---------------- MFMA bf16 GEMM + al/ar epilogue ----------------
// Block 256 (4 waves). Tile 64 rows x 128 cols, K=128. Wave w owns cols
// [32w, 32w+32). W^T staged once per block in LDS (bf16, XOR-swizzled
// 8-short chunks -> 2-way conflicts = free). Accumulators round-trip
// through Xl so xw store is coalesced and al/ar is a local per-head dot.
template<bool BF16IN>
__global__ __launch_bounds__(256) void k_gemm(
    const void* __restrict__ Xv, const float* __restrict__ W,
    const float* __restrict__ attl, const float* __restrict__ attr,
    unsigned short* __restrict__ XW, float* __restrict__ AL, float* __restrict__ AR, int n)
{
  __shared__ unsigned short Wt[128*128];   // 32 KB
  __shared__ unsigned short Xl[64*136];    // 17 KB, pitch 136 (16B-aligned rows)
  int t = threadIdx.x;
  int lane = t & 63, w = t >> 6;
  int l15 = lane & 15, quad = lane >> 4;
  // stage W^T bf16, chunk-swizzled: Wt[n][ (k/8 ^ n&15)*8 + k%8 ]
  for (int i = 0; i < 64; i++){
    int e = i*256 + t;
    int k = e >> 7, nn = e & 127;
    Wt[nn*128 + ((((k>>3) ^ (nn&15))<<3) | (k&7))] = f2bf(W[e]);
  }
  int ntiles = (n + 63) >> 6;
  int r_ = t >> 2, seg = t & 3;           // epilogue/staging mapping
  for (int tile = blockIdx.x; tile < ntiles; tile += gridDim.x){
    int row0 = tile << 6;
    __syncthreads();                      // Wt ready / prev epilogue done
    {  // stage X tile as bf16
      int grow = row0 + r_;
      unsigned short* dp = &Xl[r_*136 + seg*32];
      if (grow < n){
        if (BF16IN){
          const uint4* gp = (const uint4*)((const unsigned short*)Xv + (size_t)grow*128 + seg*32);
          #pragma unroll
          for (int i = 0; i < 4; i++) ((uint4*)dp)[i] = gp[i];
        } else {
          const float4* gp = (const float4*)((const float*)Xv + (size_t)grow*128 + seg*32);
          #pragma unroll
          for (int i = 0; i < 8; i++){
            float4 v = gp[i];
            ((unsigned*)dp)[i*2]   = (unsigned)f2bf(v.x) | ((unsigned)f2bf(v.y) << 16);
            ((unsigned*)dp)[i*2+1] = (unsigned)f2bf(v.z) | ((unsigned)f2bf(v.w) << 16);
          }
        }
      } else {
        #pragma unroll
        for (int i = 0; i < 4; i++) ((uint4*)dp)[i] = make_uint4(0,0,0,0);
      }
    }
    __syncthreads();
    f32x4 acc[4][2];
    #pragma unroll
    for (int rt = 0; rt < 4; rt++){ acc[rt][0] = (f32x4){0,0,0,0}; acc[rt][1] = (f32x4){0,0,0,0}; }
    #pragma unroll
    for (int ks = 0; ks < 4; ks++){
      s16x8 b0 = *(const s16x8*)&Wt[(w*32 + l15)*128      + (((ks*4+quad) ^ l15)<<3)];
      s16x8 b1 = *(const s16x8*)&Wt[(w*32 + 16 + l15)*128 + (((ks*4+quad) ^ l15)<<3)];
      #pragma unroll
      for (int rt = 0; rt < 4; rt++){
        s16x8 a = *(const s16x8*)&Xl[(rt*16 + l15)*136 + ks*32 + quad*8];
        acc[rt][0] = __builtin_amdgcn_mfma_f32_16x16x32_bf16(a, b0, acc[rt][0], 0, 0, 0);
        acc[rt][1] = __builtin_amdgcn_mfma_f32_16x16x32_bf16(a, b1, acc[rt][1], 0, 0, 0);
      }
    }
    __syncthreads();                      // a-reads done; Xl reusable
    // C layout: col = l15, row = quad*4 + reg
    #pragma unroll
    for (int rt = 0; rt < 4; rt++)
      #pragma unroll
      for (int c2 = 0; c2 < 2; c2++)
        #pragma unroll
        for (int r = 0; r < 4; r++)
          Xl[(rt*16 + quad*4 + r)*136 + w*32 + c2*16 + l15] = f2bf(acc[rt][c2][r]);
    __syncthreads();
    {  // epilogue: thread -> (row r_, head seg); coalesced store + local dot
      int grow = row0 + r_;
      if (grow < n){
        const unsigned short* sp = &Xl[r_*136 + seg*32];
        uint4 uu[4];
        #pragma unroll
        for (int i = 0; i < 4; i++) uu[i] = ((const uint4*)sp)[i];
        unsigned short* gx = XW + (size_t)grow*128 + seg*32;
        #pragma unroll
        for (int i = 0; i < 4; i++) ((uint4*)gx)[i] = uu[i];
        const unsigned* up = (const unsigned*)uu;
        const float4* alp = (const float4*)(attl + seg*32);
        const float4* arp = (const float4*)(attr + seg*32);
        float pl = 0.f, pr = 0.f;
        #pragma unroll
        for (int i = 0; i < 8; i++){
          unsigned ua = up[i*2], ub = up[i*2+1];
          float x0 = __uint_as_float(ua << 16);
          float x1 = __uint_as_float(ua & 0xffff0000u);
          float x2 = __uint_as_float(ub << 16);
          float x3 = __uint_as_float(ub & 0xffff0000u);
          float4 av = alp[i];
          float4 rv = arp[i];
          pl += x0*av.x + x1*av.y + x2*av.z + x3*av.w;
          pr += x0*rv.x + x1*rv.y + x2*rv.z + x3*rv.w;
        }
        AL[grow*4 + seg] = pl;
        AR[grow*4 + seg] = pr;
      }
    }
  }
}

// ---------------- Attention + aggregate: one wave per dst, single sweep ----
template<bool BF16OUT>
__global__ __launch_bounds__(256) void k_attn(
    const unsigned short* __restrict__ XW, const float* __restrict__ AL, const float* __restrict__ AR,
    const int* __restrict__ rp, const int* __restrict__ col,
    const float* __restrict__ bias, void* __restrict__ OUT, int n)
{
  __shared__ float ebuf[4][64*4];
  __shared__ int   sbuf[4][64];
  int wv = threadIdx.x >> 6;
  int d = blockIdx.x*4 + wv;
  int lane = threadIdx.x & 63;
  if (d >= n) return;
  int start = rp[d], end = rp[d+1];
  float4 ald4 = ((const float4*)AL)[d];
  float4 ard4 = ((const float4*)AR)[d];
  float ar0 = ard4.x, ar1 = ard4.y, ar2 = ard4.z, ar3 = ard4.w;
  float es0 = __expf(LRELU(ald4.x + ar0));
  float es1 = __expf(LRELU(ald4.y + ar1));
  float es2 = __expf(LRELU(ald4.z + ar2));
  float es3 = __expf(LRELU(ald4.w + ar3));
  int h = lane >> 4;
  float eself = h==0?es0 : h==1?es1 : h==2?es2 : es3;
  const unsigned* XWr = (const unsigned*)XW;
  unsigned v = XWr[(size_t)d*64 + lane];
  float acc0 = eself * __uint_as_float(v << 16);
  float acc1 = eself * __uint_as_float(v & 0xffff0000u);
  float zl0 = 0.f, zl1 = 0.f, zl2 = 0.f, zl3 = 0.f;
  float* eb = ebuf[wv];
  int*   sb = sbuf[wv];
  for (int base = start; base < end; base += 64){
    int cnt = min(64, end - base);
    int s = (lane < cnt) ? col[base + lane] : 0;
    float4 a = ((const float4*)AL)[s];
    float w0 = __expf(LRELU(a.x + ar0));
    float w1 = __expf(LRELU(a.y + ar1));
    float w2 = __expf(LRELU(a.z + ar2));
    float w3 = __expf(LRELU(a.w + ar3));
    if (lane >= cnt){ w0 = w1 = w2 = w3 = 0.f; }
    zl0 += w0; zl1 += w1; zl2 += w2; zl3 += w3;
    float4 w4; w4.x = w0; w4.y = w1; w4.z = w2; w4.w = w3;
    ((float4*)eb)[lane] = w4;
    sb[lane] = s;
    #pragma unroll 4
    for (int j = 0; j < cnt; j++){
      int sj = sb[j];
      float w = eb[j*4 + h];
      unsigned u = XWr[(size_t)sj*64 + lane];
      acc0 = fmaf(w, __uint_as_float(u << 16), acc0);
      acc1 = fmaf(w, __uint_as_float(u & 0xffff0000u), acc1);
    }
  }
  #pragma unroll
  for (int off = 32; off >= 1; off >>= 1){
    zl0 += __shfl_xor(zl0, off, 64);
    zl1 += __shfl_xor(zl1, off, 64);
    zl2 += __shfl_xor(zl2, off, 64);
    zl3 += __shfl_xor(zl3, off, 64);
  }
  float z_h = (h==0?zl0 : h==1?zl1 : h==2?zl2 : zl3) + eself;
  float rz = 1.f / z_h;
  int ch = lane*2;
  float o0 = fmaf(acc0, rz, bias[ch]);
  float o1 = fmaf(acc1, rz, bias[ch+1]);
  o0 = o0 > 0.f ? o0 : 0.f;
  o1 = o1 > 0.f ? o1 : 0.f;
  if (BF16OUT){
    unsigned pk = (unsigned)f2bf(o0) | ((unsigned)f2bf(o1) << 16);
    ((unsigned*)OUT)[(size_t)d*64 + lane] = pk;
  } else {
    float2 o; o.x = o0; o.y = o1;
    ((float2*)OUT)[(size_t)d*64 + lane] = o;
  }
}

// ---------------- pooling + MLP head ----------------
__global__ __launch_bounds__(128) void k_pool(const float* __restrict__ H,
                                              const int* __restrict__ gstart,
                                              float* __restrict__ psum){
  int g = blockIdx.x >> 3, slice = blockIdx.x & 7, t = threadIdx.x;
  int s0 = gstart[g], s1 = gstart[g+1];
  int cntg = s1 - s0;
  int chunk = (cntg + 7) >> 3;
  int lo = s0 + slice*chunk;
  int hi = min(lo + chunk, s1);
  float sum = 0.f;
  for (int i = lo; i < hi; i++) sum += H[(size_t)i*128 + t];
  atomicAdd(&psum[g*128 + t], sum);
}

__global__ __launch_bounds__(128) void k_mlp(const float* __restrict__ psum,
                       const int* __restrict__ gstart,
                       const float* __restrict__ w1, const float* __restrict__ b1,
                       const float* __restrict__ w2, const float* __restrict__ b2,
                       float* __restrict__ out)
{
  __shared__ float p[128];
  __shared__ float gsh[128];
  __shared__ float lg[10];
  int g = blockIdx.x, t = threadIdx.x;
  float c = fmaxf((float)(gstart[g+1] - gstart[g]), 1.f);
  p[t] = psum[g*128 + t] / c;
  __syncthreads();
  float acc = b1[t];
  for (int k = 0; k < 128; k++) acc = fmaf(p[k], w1[k*128 + t], acc);
  gsh[t] = acc > 0.f ? acc : 0.f;
  __syncthreads();
  if (t < 10){
    float a = b2[t];
    for (int k = 0; k < 128; k++) a = fmaf(gsh[k], w2[k*10 + t], a);
    lg[t] = a;
  }
  __syncthreads();
  if (t < 10){
    float mx = lg[0];
    for (int c2 = 1; c2 < 10; c2++) mx = fmaxf(mx, lg[c2]);
    float se = 0.f;
    for (int c2 = 0; c2 < 10; c2++) se += __expf(lg[c2] - mx);
    out[g*10 + t] = lg[t] - mx - logf(se);
  }
}

extern "C" void kernel_launch(void* const* d_in, const int* in_sizes, int n_in,
                              void* d_out, int out_size, void* d_ws, size_t ws_size,
                              hipStream_t stream)
{
  const float* x    = (const float*)d_in[0];
  const int* eidx   = (const int*)d_in[1];
  const int* batch  = (const int*)d_in[2];
  const float* W[3]  = {(const float*)d_in[3], (const float*)d_in[7],  (const float*)d_in[11]};
  const float* al[3] = {(const float*)d_in[4], (const float*)d_in[8],  (const float*)d_in[12]};
  const float* ar[3] = {(const float*)d_in[5], (const float*)d_in[9],  (const float*)d_in[13]};
  const float* bs[3] = {(const float*)d_in[6], (const float*)d_in[10], (const float*)d_in[14]};
  const float* l1w = (const float*)d_in[15];
  const float* l1b = (const float*)d_in[16];
  const float* l2w = (const float*)d_in[17];
  const float* l2b = (const float*)d_in[18];
  int E = in_sizes[1] / 2;
  int n = in_sizes[2];            // 100000
  const int* srcp = eidx;
  const int* dstp = eidx + E;
  int NB = (n + 127) >> SH;       // 782 buckets (<=1024)

  char* wsp = (char*)d_ws;
  auto alloc = [&](size_t bytes){ void* p = (void*)wsp; wsp += (bytes + 255) & ~(size_t)255; return p; };
  unsigned short* xw   = (unsigned short*)alloc((size_t)n*128*2);  // 25.6 MB bf16
  unsigned short* hbuf = (unsigned short*)alloc((size_t)n*128*2);  // 25.6 MB bf16
  float* ALb  = (float*)alloc((size_t)n*4*4);
  float* ARb  = (float*)alloc((size_t)n*4*4);
  int* rp     = (int*)alloc((size_t)(n+1)*4);
  int* col    = (int*)alloc((size_t)E*4);          // 6.4 MB
  int2* tmp   = (int2*)alloc((size_t)E*8);         // 12.8 MB bucketed pairs
  int* bcnt   = (int*)alloc(1024*4);
  int* bstart = (int*)alloc(1025*4);
  int* bfill  = (int*)alloc(1024*4);
  float* psum = (float*)alloc(64*128*4);
  int* gstart = (int*)alloc(65*4);

  float* outlog = (float*)d_out;
  float* h3     = (float*)d_out + 64*10;

  hipMemsetAsync(bcnt, 0, 1024*4,   stream);
  hipMemsetAsync(psum, 0, 64*128*4, stream);

  // CSR build
  int nparts = (E + TILE - 1) / TILE;
  k_bcnt <<<nparts, 256, 0, stream>>>(dstp, bcnt, E, NB);
  k_bscan<<<1, 256, 0, stream>>>(bcnt, bstart, bfill, NB, E);
  k_part <<<nparts, 256, 0, stream>>>(srcp, dstp, bfill, tmp, E);
  k_csr  <<<NB, 256, 0, stream>>>(tmp, bstart, rp, col, n, E);

  k_bounds<<<1, 128, 0, stream>>>(batch, gstart, n);

  const int GG = 768;   // 3 blocks/CU (50 KB LDS each)
  // layer 1 (fp32 in, bf16 h out)
  k_gemm<false><<<GG, 256, 0, stream>>>(x, W[0], al[0], ar[0], xw, ALb, ARb, n);
  k_attn<true><<<(n+3)/4, 256, 0, stream>>>(xw, ALb, ARb, rp, col, bs[0], hbuf, n);
  // layer 2 (bf16 in, bf16 h out)
  k_gemm<true><<<GG, 256, 0, stream>>>(hbuf, W[1], al[1], ar[1], xw, ALb, ARb, n);
  k_attn<true><<<(n+3)/4, 256, 0, stream>>>(xw, ALb, ARb, rp, col, bs[1], hbuf, n);
  // layer 3 (bf16 in, fp32 out straight into d_out)
  k_gemm<true><<<GG, 256, 0, stream>>>(hbuf, W[2], al[2], ar[2], xw, ALb, ARb, n);
  k_attn<false><<<(n+3)/4, 256, 0, stream>>>(xw, ALb, ARb, rp, col, bs[2], h3, n);

  k_pool<<<64*8, 128, 0, stream>>>(h3, gstart, psum);
  k_mlp <<<64, 128, 0, stream>>>(psum, gstart, l1w, l1b, l2w, l2b, outlog);
}

// Round 7
// 580.856 us; speedup vs baseline: 3.0140x; 1.0327x over previous
//
#include <hip/hip_runtime.h>
#include <math.h>

// GAT 3-layer, MI355X. Round 6:
// (1) GEMM-1 fused into the bcnt dispatch (independent work, co-runs).
// (2) SH 7->8: longer bucket runs in k_part (fewer scattered-write txns).
// (3) k_init replaces memsets; bounds folded into bscan. 12 dispatches.
// (4) attn micro-opts (premultiplied src offset, unroll 8).

#define LRELU(x) ((x) > 0.f ? (x) : 0.2f*(x))
#define SH 8          // bucket = dst >> 8 (256 nodes per bucket)
#define TILE 4096
#define EPT 16

typedef __attribute__((ext_vector_type(8))) short s16x8;
typedef __attribute__((ext_vector_type(4))) float f32x4;

__device__ inline unsigned short f2bf(float f){
  unsigned u = __float_as_uint(f);
  u += 0x7fff + ((u >> 16) & 1);   // round-to-nearest-even
  return (unsigned short)(u >> 16);
}

// ---------------- init: zero bcnt + psum ----------------
__global__ void k_init(int* __restrict__ bcnt, float* __restrict__ psum){
  int t = threadIdx.x;
  bcnt[t] = 0; bcnt[256 + t] = 0;
  for (int i = t; i < 8192; i += 256) psum[i] = 0.f;
}

// ---------------- MFMA bf16 GEMM body (shared by k_gemm / k_fuse1) -------
// Block 256 (4 waves). Tile 64 rows x 128 cols, K=128. Wave w owns cols
// [32w, 32w+32). W^T staged once per block in LDS (bf16, XOR-swizzled).
// Accumulators round-trip through Xl -> coalesced xw store + local al/ar dot.
template<bool BF16IN>
__device__ __forceinline__ void gemm_body(
    unsigned short* Wt, unsigned short* Xl,
    const void* __restrict__ Xv, const float* __restrict__ W,
    const float* __restrict__ attl, const float* __restrict__ attr,
    unsigned short* __restrict__ XW, float* __restrict__ AL, float* __restrict__ AR,
    int n, int bid, int gstride)
{
  int t = threadIdx.x;
  int lane = t & 63, w = t >> 6;
  int l15 = lane & 15, quad = lane >> 4;
  // stage W^T bf16, chunk-swizzled: Wt[n][ ((k/8 ^ (n&15))*8 + k%8 ]
  for (int i = 0; i < 64; i++){
    int e = i*256 + t;
    int k = e >> 7, nn = e & 127;
    Wt[nn*128 + ((((k>>3) ^ (nn&15))<<3) | (k&7))] = f2bf(W[e]);
  }
  int ntiles = (n + 63) >> 6;
  int r_ = t >> 2, seg = t & 3;
  for (int tile = bid; tile < ntiles; tile += gstride){
    int row0 = tile << 6;
    __syncthreads();
    {  // stage X tile as bf16
      int grow = row0 + r_;
      unsigned short* dp = &Xl[r_*136 + seg*32];
      if (grow < n){
        if (BF16IN){
          const uint4* gp = (const uint4*)((const unsigned short*)Xv + (size_t)grow*128 + seg*32);
          #pragma unroll
          for (int i = 0; i < 4; i++) ((uint4*)dp)[i] = gp[i];
        } else {
          const float4* gp = (const float4*)((const float*)Xv + (size_t)grow*128 + seg*32);
          #pragma unroll
          for (int i = 0; i < 8; i++){
            float4 v = gp[i];
            ((unsigned*)dp)[i*2]   = (unsigned)f2bf(v.x) | ((unsigned)f2bf(v.y) << 16);
            ((unsigned*)dp)[i*2+1] = (unsigned)f2bf(v.z) | ((unsigned)f2bf(v.w) << 16);
          }
        }
      } else {
        #pragma unroll
        for (int i = 0; i < 4; i++) ((uint4*)dp)[i] = make_uint4(0,0,0,0);
      }
    }
    __syncthreads();
    f32x4 acc[4][2];
    #pragma unroll
    for (int rt = 0; rt < 4; rt++){ acc[rt][0] = (f32x4){0,0,0,0}; acc[rt][1] = (f32x4){0,0,0,0}; }
    #pragma unroll
    for (int ks = 0; ks < 4; ks++){
      s16x8 b0 = *(const s16x8*)&Wt[(w*32 + l15)*128      + (((ks*4+quad) ^ l15)<<3)];
      s16x8 b1 = *(const s16x8*)&Wt[(w*32 + 16 + l15)*128 + (((ks*4+quad) ^ l15)<<3)];
      #pragma unroll
      for (int rt = 0; rt < 4; rt++){
        s16x8 a = *(const s16x8*)&Xl[(rt*16 + l15)*136 + ks*32 + quad*8];
        acc[rt][0] = __builtin_amdgcn_mfma_f32_16x16x32_bf16(a, b0, acc[rt][0], 0, 0, 0);
        acc[rt][1] = __builtin_amdgcn_mfma_f32_16x16x32_bf16(a, b1, acc[rt][1], 0, 0, 0);
      }
    }
    __syncthreads();
    // C layout: col = l15, row = quad*4 + reg
    #pragma unroll
    for (int rt = 0; rt < 4; rt++)
      #pragma unroll
      for (int c2 = 0; c2 < 2; c2++)
        #pragma unroll
        for (int r = 0; r < 4; r++)
          Xl[(rt*16 + quad*4 + r)*136 + w*32 + c2*16 + l15] = f2bf(acc[rt][c2][r]);
    __syncthreads();
    {  // epilogue: thread -> (row r_, head seg)
      int grow = row0 + r_;
      if (grow < n){
        const unsigned short* sp = &Xl[r_*136 + seg*32];
        uint4 uu[4];
        #pragma unroll
        for (int i = 0; i < 4; i++) uu[i] = ((const uint4*)sp)[i];
        unsigned short* gx = XW + (size_t)grow*128 + seg*32;
        #pragma unroll
        for (int i = 0; i < 4; i++) ((uint4*)gx)[i] = uu[i];
        const unsigned* up = (const unsigned*)uu;
        const float4* alp = (const float4*)(attl + seg*32);
        const float4* arp = (const float4*)(attr + seg*32);
        float pl = 0.f, pr = 0.f;
        #pragma unroll
        for (int i = 0; i < 8; i++){
          unsigned ua = up[i*2], ub = up[i*2+1];
          float x0 = __uint_as_float(ua << 16);
          float x1 = __uint_as_float(ua & 0xffff0000u);
          float x2 = __uint_as_float(ub << 16);
          float x3 = __uint_as_float(ub & 0xffff0000u);
          float4 av = alp[i];
          float4 rv = arp[i];
          pl += x0*av.x + x1*av.y + x2*av.z + x3*av.w;
          pr += x0*rv.x + x1*rv.y + x2*rv.z + x3*rv.w;
        }
        AL[grow*4 + seg] = pl;
        AR[grow*4 + seg] = pr;
      }
    }
  }
}

template<bool BF16IN>
__global__ __launch_bounds__(256) void k_gemm(
    const void* __restrict__ Xv, const float* __restrict__ W,
    const float* __restrict__ attl, const float* __restrict__ attr,
    unsigned short* __restrict__ XW, float* __restrict__ AL, float* __restrict__ AR, int n)
{
  __shared__ unsigned short Wt[128*128];
  __shared__ unsigned short Xl[64*136];
  gemm_body<BF16IN>(Wt, Xl, Xv, W, attl, attr, XW, AL, AR, n, blockIdx.x, gridDim.x);
}

// ---------------- fused: bucket histogram (blocks < nparts) + GEMM-1 ----
__global__ __launch_bounds__(256) void k_fuse1(
    const int* __restrict__ dst, int* __restrict__ bcnt, int E, int nparts,
    const float* __restrict__ X, const float* __restrict__ W,
    const float* __restrict__ attl, const float* __restrict__ attr,
    unsigned short* __restrict__ XW, float* __restrict__ AL, float* __restrict__ AR, int n)
{
  __shared__ unsigned short Wt[128*128];
  __shared__ unsigned short Xl[64*136];
  if ((int)blockIdx.x < nparts){
    int* lh = (int*)Wt;     // alias histogram onto Wt
    int t = threadIdx.x;
    for (int j = t; j < 512; j += 256) lh[j] = 0;
    __syncthreads();
    int base = blockIdx.x * TILE;
    int lim = min(base + TILE, E);
    for (int e = base + t; e < lim; e += 256)
      atomicAdd(&lh[dst[e] >> SH], 1);
    __syncthreads();
    for (int j = t; j < 512; j += 256){
      int v = lh[j];
      if (v) atomicAdd(&bcnt[j], v);
    }
    return;
  }
  gemm_body<false>(Wt, Xl, X, W, attl, attr, XW, AL, AR, n,
                   (int)blockIdx.x - nparts, (int)gridDim.x - nparts);
}

// ---------------- bucket scan (block 0) + graph bounds (block 1) --------
__global__ __launch_bounds__(256) void k_bscan(const int* __restrict__ bcnt,
    int* __restrict__ bstart, int* __restrict__ bfill, int NB, int E,
    const int* __restrict__ batch, int* __restrict__ gstart, int n){
  int t = threadIdx.x;
  if (blockIdx.x == 1){
    int g = t;
    if (g > 64) return;
    int lo = 0, hi = n;
    while (lo < hi){
      int mid = (lo + hi) >> 1;
      if (batch[mid] < g) lo = mid + 1; else hi = mid;
    }
    gstart[g] = lo;
    return;
  }
  __shared__ int c[512];
  __shared__ int ps[256];
  for (int j = t; j < 512; j += 256) c[j] = (j < NB) ? bcnt[j] : 0;
  __syncthreads();
  int b0 = 2*t;
  int v0 = c[b0], v1 = c[b0+1];
  int ts = v0 + v1;
  ps[t] = ts; __syncthreads();
  for (int off = 1; off < 256; off <<= 1){
    int x = (t >= off) ? ps[t-off] : 0; __syncthreads();
    ps[t] += x; __syncthreads();
  }
  int pre = ps[t] - ts;
  if (b0   < NB){ bstart[b0]   = pre;    bfill[b0]   = pre; }
  if (b0+1 < NB){ bstart[b0+1] = pre+v0; bfill[b0+1] = pre+v0; }
  if (t == 0) bstart[NB] = E;
}

// LDS multi-split: tile of 4096 edges ranked by bucket, flushed as
// bucket-contiguous runs (~10-edge bursts at SH=8).
__global__ __launch_bounds__(256) void k_part(const int* __restrict__ src,
    const int* __restrict__ dst, int* __restrict__ bfill,
    int2* __restrict__ tmp, int E){
  __shared__ int2 reorder[TILE];
  __shared__ int lhist[512], lscan[512], lgbase[512];
  __shared__ int ps[256];
  int t = threadIdx.x;
  int tb = blockIdx.x * TILE;
  int tilecnt = min(TILE, E - tb);
  for (int j = t; j < 512; j += 256) lhist[j] = 0;
  __syncthreads();
  int ss[EPT], dd[EPT], rk[EPT];
  #pragma unroll
  for (int i = 0; i < EPT; i++){
    int e = tb + t + i*256;
    if (e < E){
      ss[i] = src[e]; dd[i] = dst[e];
      rk[i] = atomicAdd(&lhist[dd[i] >> SH], 1);
    }
  }
  __syncthreads();
  int b0 = 2*t;
  int v0 = lhist[b0], v1 = lhist[b0+1];
  int ts = v0 + v1;
  ps[t] = ts; __syncthreads();
  for (int off = 1; off < 256; off <<= 1){
    int x = (t >= off) ? ps[t-off] : 0; __syncthreads();
    ps[t] += x; __syncthreads();
  }
  int pre = ps[t] - ts;
  int ex0 = pre, ex1 = pre + v0;
  lscan[b0] = ex0; lscan[b0+1] = ex1;
  if (v0 > 0){ int gb = atomicAdd(&bfill[b0],   v0); lgbase[b0]   = gb - ex0; }
  if (v1 > 0){ int gb = atomicAdd(&bfill[b0+1], v1); lgbase[b0+1] = gb - ex1; }
  __syncthreads();
  #pragma unroll
  for (int i = 0; i < EPT; i++){
    int e = tb + t + i*256;
    if (e < E){
      int b = dd[i] >> SH;
      reorder[lscan[b] + rk[i]] = make_int2(ss[i], dd[i]);
    }
  }
  __syncthreads();
  for (int j = t; j < tilecnt; j += 256){
    int2 p = reorder[j];
    tmp[lgbase[p.y >> SH] + j] = p;
  }
}

// One block per bucket (256 nodes): per-node offsets via LDS scan (-> rp),
// then scatter src into the bucket's ~16KB col window (single-CU, merges).
__global__ __launch_bounds__(256) void k_csr(const int2* __restrict__ tmp,
    const int* __restrict__ bstart, int* __restrict__ rp, int* __restrict__ col,
    int n, int E){
  __shared__ int lcnt[256];
  __shared__ int sc[256];
  int b = blockIdx.x, t = threadIdx.x;
  int node0 = b << SH;
  int ncnt = min(256, n - node0);
  int be = bstart[b], ee = bstart[b+1];
  lcnt[t] = 0;
  __syncthreads();
  for (int e = be + t; e < ee; e += 256)
    atomicAdd(&lcnt[tmp[e].y - node0], 1);
  __syncthreads();
  int v = lcnt[t];
  sc[t] = v;
  __syncthreads();
  for (int off = 1; off < 256; off <<= 1){
    int x = (t >= off) ? sc[t-off] : 0;
    __syncthreads();
    sc[t] += x;
    __syncthreads();
  }
  int start = be + sc[t] - v;     // exclusive
  lcnt[t] = start;
  if (t < ncnt) rp[node0 + t] = start;
  if (t == 0 && node0 + ncnt == n) rp[n] = E;
  __syncthreads();
  for (int e = be + t; e < ee; e += 256){
    int2 p = tmp[e];
    int pos = atomicAdd(&lcnt[p.y - node0], 1);
    col[pos] = p.x;
  }
}

// ---------------- Attention + aggregate: one wave per dst, single sweep ----
template<bool BF16OUT>
__global__ __launch_bounds__(256) void k_attn(
    const unsigned short* __restrict__ XW, const float* __restrict__ AL, const float* __restrict__ AR,
    const int* __restrict__ rp, const int* __restrict__ col,
    const float* __restrict__ bias, void* __restrict__ OUT, int n)
{
  __shared__ float ebuf[4][64*4];
  __shared__ int   sbuf[4][64];
  int wv = threadIdx.x >> 6;
  int d = blockIdx.x*4 + wv;
  int lane = threadIdx.x & 63;
  if (d >= n) return;
  int start = rp[d], end = rp[d+1];
  float4 ald4 = ((const float4*)AL)[d];
  float4 ard4 = ((const float4*)AR)[d];
  float ar0 = ard4.x, ar1 = ard4.y, ar2 = ard4.z, ar3 = ard4.w;
  float es0 = __expf(LRELU(ald4.x + ar0));
  float es1 = __expf(LRELU(ald4.y + ar1));
  float es2 = __expf(LRELU(ald4.z + ar2));
  float es3 = __expf(LRELU(ald4.w + ar3));
  int h = lane >> 4;
  float eself = h==0?es0 : h==1?es1 : h==2?es2 : es3;
  const unsigned* XWr = (const unsigned*)XW;
  unsigned v = XWr[(unsigned)d*64 + lane];
  float acc0 = eself * __uint_as_float(v << 16);
  float acc1 = eself * __uint_as_float(v & 0xffff0000u);
  float zl0 = 0.f, zl1 = 0.f, zl2 = 0.f, zl3 = 0.f;
  float* eb = ebuf[wv];
  int*   sb = sbuf[wv];
  for (int base = start; base < end; base += 64){
    int cnt = min(64, end - base);
    int s = (lane < cnt) ? col[base + lane] : 0;
    float4 a = ((const float4*)AL)[s];
    float w0 = __expf(LRELU(a.x + ar0));
    float w1 = __expf(LRELU(a.y + ar1));
    float w2 = __expf(LRELU(a.z + ar2));
    float w3 = __expf(LRELU(a.w + ar3));
    if (lane >= cnt){ w0 = w1 = w2 = w3 = 0.f; }
    zl0 += w0; zl1 += w1; zl2 += w2; zl3 += w3;
    float4 w4; w4.x = w0; w4.y = w1; w4.z = w2; w4.w = w3;
    ((float4*)eb)[lane] = w4;
    sb[lane] = s << 6;              // premultiplied uint index base
    #pragma unroll 8
    for (int j = 0; j < cnt; j++){
      unsigned sj = (unsigned)sb[j] + lane;
      float w = eb[j*4 + h];
      unsigned u = XWr[sj];
      acc0 = fmaf(w, __uint_as_float(u << 16), acc0);
      acc1 = fmaf(w, __uint_as_float(u & 0xffff0000u), acc1);
    }
  }
  #pragma unroll
  for (int off = 32; off >= 1; off >>= 1){
    zl0 += __shfl_xor(zl0, off, 64);
    zl1 += __shfl_xor(zl1, off, 64);
    zl2 += __shfl_xor(zl2, off, 64);
    zl3 += __shfl_xor(zl3, off, 64);
  }
  float z_h = (h==0?zl0 : h==1?zl1 : h==2?zl2 : zl3) + eself;
  float rz = 1.f / z_h;
  int ch = lane*2;
  float o0 = fmaf(acc0, rz, bias[ch]);
  float o1 = fmaf(acc1, rz, bias[ch+1]);
  o0 = o0 > 0.f ? o0 : 0.f;
  o1 = o1 > 0.f ? o1 : 0.f;
  if (BF16OUT){
    unsigned pk = (unsigned)f2bf(o0) | ((unsigned)f2bf(o1) << 16);
    ((unsigned*)OUT)[(unsigned)d*64 + lane] = pk;
  } else {
    float2 o; o.x = o0; o.y = o1;
    ((float2*)OUT)[(unsigned)d*64 + lane] = o;
  }
}

// ---------------- pooling + MLP head ----------------
__global__ __launch_bounds__(128) void k_pool(const float* __restrict__ H,
                                              const int* __restrict__ gstart,
                                              float* __restrict__ psum){
  int g = blockIdx.x >> 3, slice = blockIdx.x & 7, t = threadIdx.x;
  int s0 = gstart[g], s1 = gstart[g+1];
  int cntg = s1 - s0;
  int chunk = (cntg + 7) >> 3;
  int lo = s0 + slice*chunk;
  int hi = min(lo + chunk, s1);
  float sum = 0.f;
  for (int i = lo; i < hi; i++) sum += H[(size_t)i*128 + t];
  atomicAdd(&psum[g*128 + t], sum);
}

__global__ __launch_bounds__(128) void k_mlp(const float* __restrict__ psum,
                       const int* __restrict__ gstart,
                       const float* __restrict__ w1, const float* __restrict__ b1,
                       const float* __restrict__ w2, const float* __restrict__ b2,
                       float* __restrict__ out)
{
  __shared__ float p[128];
  __shared__ float gsh[128];
  __shared__ float lg[10];
  int g = blockIdx.x, t = threadIdx.x;
  float c = fmaxf((float)(gstart[g+1] - gstart[g]), 1.f);
  p[t] = psum[g*128 + t] / c;
  __syncthreads();
  float acc = b1[t];
  for (int k = 0; k < 128; k++) acc = fmaf(p[k], w1[k*128 + t], acc);
  gsh[t] = acc > 0.f ? acc : 0.f;
  __syncthreads();
  if (t < 10){
    float a = b2[t];
    for (int k = 0; k < 128; k++) a = fmaf(gsh[k], w2[k*10 + t], a);
    lg[t] = a;
  }
  __syncthreads();
  if (t < 10){
    float mx = lg[0];
    for (int c2 = 1; c2 < 10; c2++) mx = fmaxf(mx, lg[c2]);
    float se = 0.f;
    for (int c2 = 0; c2 < 10; c2++) se += __expf(lg[c2] - mx);
    out[g*10 + t] = lg[t] - mx - logf(se);
  }
}

extern "C" void kernel_launch(void* const* d_in, const int* in_sizes, int n_in,
                              void* d_out, int out_size, void* d_ws, size_t ws_size,
                              hipStream_t stream)
{
  const float* x    = (const float*)d_in[0];
  const int* eidx   = (const int*)d_in[1];
  const int* batch  = (const int*)d_in[2];
  const float* W[3]  = {(const float*)d_in[3], (const float*)d_in[7],  (const float*)d_in[11]};
  const float* al[3] = {(const float*)d_in[4], (const float*)d_in[8],  (const float*)d_in[12]};
  const float* ar[3] = {(const float*)d_in[5], (const float*)d_in[9],  (const float*)d_in[13]};
  const float* bs[3] = {(const float*)d_in[6], (const float*)d_in[10], (const float*)d_in[14]};
  const float* l1w = (const float*)d_in[15];
  const float* l1b = (const float*)d_in[16];
  const float* l2w = (const float*)d_in[17];
  const float* l2b = (const float*)d_in[18];
  int E = in_sizes[1] / 2;
  int n = in_sizes[2];            // 100000
  const int* srcp = eidx;
  const int* dstp = eidx + E;
  int NB = (n + 255) >> SH;       // 391 buckets (<=512)

  char* wsp = (char*)d_ws;
  auto alloc = [&](size_t bytes){ void* p = (void*)wsp; wsp += (bytes + 255) & ~(size_t)255; return p; };
  unsigned short* xw   = (unsigned short*)alloc((size_t)n*128*2);  // 25.6 MB bf16
  unsigned short* hbuf = (unsigned short*)alloc((size_t)n*128*2);  // 25.6 MB bf16
  float* ALb  = (float*)alloc((size_t)n*4*4);
  float* ARb  = (float*)alloc((size_t)n*4*4);
  int* rp     = (int*)alloc((size_t)(n+1)*4);
  int* col    = (int*)alloc((size_t)E*4);          // 6.4 MB
  int2* tmp   = (int2*)alloc((size_t)E*8);         // 12.8 MB bucketed pairs
  int* bcnt   = (int*)alloc(512*4);
  int* bstart = (int*)alloc(513*4);
  int* bfill  = (int*)alloc(512*4);
  float* psum = (float*)alloc(64*128*4);
  int* gstart = (int*)alloc(65*4);

  float* outlog = (float*)d_out;
  float* h3     = (float*)d_out + 64*10;

  int nparts = (E + TILE - 1) / TILE;   // 391

  k_init<<<1, 256, 0, stream>>>(bcnt, psum);
  // fused: bucket histogram + layer-1 GEMM (independent, co-resident)
  k_fuse1<<<nparts + 768, 256, 0, stream>>>(dstp, bcnt, E, nparts,
                                            x, W[0], al[0], ar[0], xw, ALb, ARb, n);
  k_bscan<<<2, 256, 0, stream>>>(bcnt, bstart, bfill, NB, E, batch, gstart, n);
  k_part <<<nparts, 256, 0, stream>>>(srcp, dstp, bfill, tmp, E);
  k_csr  <<<NB, 256, 0, stream>>>(tmp, bstart, rp, col, n, E);

  // layer 1 attention (xw ready from fuse1)
  k_attn<true><<<(n+3)/4, 256, 0, stream>>>(xw, ALb, ARb, rp, col, bs[0], hbuf, n);
  // layer 2
  k_gemm<true><<<768, 256, 0, stream>>>(hbuf, W[1], al[1], ar[1], xw, ALb, ARb, n);
  k_attn<true><<<(n+3)/4, 256, 0, stream>>>(xw, ALb, ARb, rp, col, bs[1], hbuf, n);
  // layer 3 -> fp32 straight into d_out
  k_gemm<true><<<768, 256, 0, stream>>>(hbuf, W[2], al[2], ar[2], xw, ALb, ARb, n);
  k_attn<false><<<(n+3)/4, 256, 0, stream>>>(xw, ALb, ARb, rp, col, bs[2], h3, n);

  k_pool<<<64*8, 128, 0, stream>>>(h3, gstart, psum);
  k_mlp <<<64, 128, 0, stream>>>(psum, gstart, l1w, l1b, l2w, l2b, outlog);
}